// Round 4
// baseline (455.734 us; speedup 1.0000x reference)
//
#include <hip/hip_runtime.h>
#include <math.h>

#define DD 1024   // hidden dim
#define HH 1408   // moe inter dim
#define NE 8      // experts

typedef __attribute__((ext_vector_type(8))) __bf16 bf16x8;
typedef __attribute__((ext_vector_type(4))) float f32x4;

__device__ __forceinline__ float bf2f(unsigned short u) {
  union { unsigned int i; float f; } v; v.i = ((unsigned int)u) << 16; return v.f;
}
__device__ __forceinline__ unsigned short f2bf(float f) {
  union { float f; unsigned int i; } v; v.f = f;
  unsigned int r = v.i + 0x7FFFu + ((v.i >> 16) & 1u);  // RNE
  return (unsigned short)(r >> 16);
}
__device__ __forceinline__ float tof(float f) { return f; }
__device__ __forceinline__ float tof(unsigned short u) { return bf2f(u); }

// pack bf16(a) | bf16(b)<<16 in ONE instruction (RNE, gfx950)
__device__ __forceinline__ void cvt2(float a, float b, unsigned int* o) {
  asm("v_cvt_pk_bf16_f32 %0, %1, %2" : "=v"(*o) : "v"(a), "v"(b));
}

__device__ __forceinline__ void ld8cvt(const float* p, unsigned int* o) {
  float4 a = *(const float4*)p;
  float4 b = *(const float4*)(p + 4);
  cvt2(a.x, a.y, o + 0); cvt2(a.z, a.w, o + 1);
  cvt2(b.x, b.y, o + 2); cvt2(b.z, b.w, o + 3);
}

// async global->LDS, 16 bytes per lane; LDS dest must be wave-uniform base
typedef unsigned int __attribute__((address_space(1))) gu32;
typedef unsigned int __attribute__((address_space(3))) lu32;
__device__ __forceinline__ void gl16(const unsigned short* g, unsigned short* l) {
  __builtin_amdgcn_global_load_lds((const gu32*)g, (lu32*)l, 16, 0, 0);
}

// ---------------- sniff input dtype: 1 = fp32, 0 = bf16 ----------------
__global__ void sniff_kernel(const unsigned short* __restrict__ xw,
                             int* __restrict__ dflag) {
  __shared__ int cnt;
  if (threadIdx.x == 0) cnt = 0;
  __syncthreads();
  unsigned short v = xw[threadIdx.x];
  int e = (v >> 7) & 0xFF;
  if (e >= 100 && e <= 140) atomicAdd(&cnt, 1);
  __syncthreads();
  if (threadIdx.x == 0) dflag[0] = (cnt < 230) ? 1 : 0;
}

// ---------------- convert x -> bf16 ----------------
__global__ void cvtx_kernel(const void* __restrict__ x,
                            const int* __restrict__ dflag,
                            unsigned short* __restrict__ xb, int n8) {
  int i = blockIdx.x * blockDim.x + threadIdx.x;
  int st = gridDim.x * blockDim.x;
  if (dflag[0]) {
    const float* xs = (const float*)x;
    for (; i < n8; i += st) {
      unsigned int o[4];
      ld8cvt(xs + (size_t)i * 8, o);
      *(uint4*)(xb + (size_t)i * 8) = *(uint4*)o;
    }
  } else {
    const uint4* xs = (const uint4*)x;
    for (; i < n8; i += st) *(uint4*)(xb + (size_t)i * 8) = xs[i];
  }
}

// ---------------- transpose+convert weights: [mat][R][C] -> [mat][C][R] bf16 ----
__global__ void trans_kernel(const void* __restrict__ wmain,
                             const void* __restrict__ wsh,
                             const int* __restrict__ dflag,
                             unsigned short* __restrict__ out, int R, int C) {
  __shared__ float tile[32][33];
  const int mat = blockIdx.z;
  const int r0 = blockIdx.y << 5, c0 = blockIdx.x << 5;
  const int t = threadIdx.x;                 // 256 threads
  const int lr = t >> 3, lc = (t & 7) << 2;
  const size_t mbase = (size_t)mat * R * C;
  if (dflag[0]) {
    const float* src = (mat < NE) ? ((const float*)wmain + mbase) : (const float*)wsh;
    float4 v = *(const float4*)(src + (size_t)(r0 + lr) * C + c0 + lc);
    tile[lr][lc] = v.x; tile[lr][lc + 1] = v.y;
    tile[lr][lc + 2] = v.z; tile[lr][lc + 3] = v.w;
  } else {
    const unsigned short* src = (mat < NE) ? ((const unsigned short*)wmain + mbase)
                                           : (const unsigned short*)wsh;
    ushort4 v = *(const ushort4*)(src + (size_t)(r0 + lr) * C + c0 + lc);
    tile[lr][lc] = bf2f(v.x); tile[lr][lc + 1] = bf2f(v.y);
    tile[lr][lc + 2] = bf2f(v.z); tile[lr][lc + 3] = bf2f(v.w);
  }
  __syncthreads();
  const int oc = t >> 3;
  const int orr = (t & 7) << 2;
  unsigned int p0, p1;
  cvt2(tile[orr][oc], tile[orr + 1][oc], &p0);
  cvt2(tile[orr + 2][oc], tile[orr + 3][oc], &p1);
  uint2 pk; pk.x = p0; pk.y = p1;
  *(uint2*)(out + mbase + (size_t)(c0 + oc) * R + r0 + orr) = pk;
}

// ---------------- biases -> f32, [NE+1] stacked (slot NE = shared) ----------
__global__ void cvtb_kernel(const void* b1, const void* b3, const void* b2,
                            const void* sb1, const void* sb3, const void* sb2,
                            const int* __restrict__ dflag,
                            float* __restrict__ bf1, float* __restrict__ bf3,
                            float* __restrict__ bf2o) {
  int i = blockIdx.x * blockDim.x + threadIdx.x;
  const int nh = (NE + 1) * HH, nd = (NE + 1) * DD;
  const bool f32 = dflag[0] != 0;
  auto get = [&](const void* pm, const void* ps, int idx, int per) -> float {
    int mat = idx / per, j = idx - mat * per;
    if (f32) return (mat < NE) ? ((const float*)pm)[(size_t)mat * per + j]
                               : ((const float*)ps)[j];
    return bf2f((mat < NE) ? ((const unsigned short*)pm)[(size_t)mat * per + j]
                           : ((const unsigned short*)ps)[j]);
  };
  if (i < nh) bf1[i] = get(b1, sb1, i, HH);
  else if (i < 2 * nh) bf3[i - nh] = get(b3, sb3, i - nh, HH);
  else if (i < 2 * nh + nd) bf2o[i - 2 * nh] = get(b2, sb2, i - 2 * nh, DD);
}

// ---------------- gate: one wave per token ----------------
template <class T>
__device__ void gate_body(const T* __restrict__ x,
                          const T* __restrict__ gw,
                          const T* __restrict__ gb,
                          int* __restrict__ tok_eidx,
                          float* __restrict__ tok_w, int T_) {
  int t = (int)((blockIdx.x * blockDim.x + threadIdx.x) >> 6);
  int lane = threadIdx.x & 63;
  if (t >= T_) return;
  const T* xr = x + (size_t)t * DD;
  float acc[NE];
#pragma unroll
  for (int e = 0; e < NE; e++) acc[e] = 0.f;
  for (int i = lane; i < DD; i += 64) {
    float xv = tof(xr[i]);
#pragma unroll
    for (int e = 0; e < NE; e++) acc[e] += xv * tof(gw[e * DD + i]);
  }
#pragma unroll
  for (int off = 32; off > 0; off >>= 1) {
#pragma unroll
    for (int e = 0; e < NE; e++) acc[e] += __shfl_xor(acc[e], off);
  }
  if (lane == 0) {
    float mx = acc[0];
#pragma unroll
    for (int e = 1; e < NE; e++) mx = fmaxf(mx, acc[e]);
    float s = 0.f, sc[NE], bi[NE];
#pragma unroll
    for (int e = 0; e < NE; e++) { sc[e] = expf(acc[e] - mx); s += sc[e]; }
    float inv = 1.f / s;
#pragma unroll
    for (int e = 0; e < NE; e++) { sc[e] *= inv; bi[e] = sc[e] + tof(gb[e]); }
    int i1 = 0;
#pragma unroll
    for (int e = 1; e < NE; e++) if (bi[e] > bi[i1]) i1 = e;
    int i2 = (i1 == 0) ? 1 : 0;
#pragma unroll
    for (int e = 0; e < NE; e++) if (e != i1 && bi[e] > bi[i2]) i2 = e;
    tok_eidx[t * 2] = i1; tok_eidx[t * 2 + 1] = i2;
    tok_w[t * 2] = sc[i1]; tok_w[t * 2 + 1] = sc[i2];
  }
}

__global__ void gate_kernel(const void* x, const void* gw, const void* gb,
                            const int* __restrict__ dflag,
                            int* tok_eidx, float* tok_w, int T_) {
  if (dflag[0])
    gate_body<float>((const float*)x, (const float*)gw, (const float*)gb,
                     tok_eidx, tok_w, T_);
  else
    gate_body<unsigned short>((const unsigned short*)x, (const unsigned short*)gw,
                              (const unsigned short*)gb, tok_eidx, tok_w, T_);
}

// ---------------- fused count + scan + scatter (single block) ----------------
__global__ void prep_kernel(const int* __restrict__ tok_eidx,
                            const float* __restrict__ tok_w,
                            int* __restrict__ meta,
                            int* __restrict__ rows_tok,
                            float* __restrict__ rows_wgt,
                            int t0, int TS) {
  __shared__ int cnt[NE];
  __shared__ int off[NE];
  const int tid = threadIdx.x;
  if (tid < NE) cnt[tid] = 0;
  __syncthreads();
  const int n2 = TS * 2;
  const int* te = tok_eidx + (size_t)t0 * 2;
  const float* tw = tok_w + (size_t)t0 * 2;
  for (int i = tid; i < n2; i += (int)blockDim.x) atomicAdd(&cnt[te[i]], 1);
  __syncthreads();
  if (tid == 0) {
    int s = 0;
#pragma unroll
    for (int e = 0; e < NE; e++) { off[e] = s; meta[16 + e] = s; s += cnt[e]; }
    meta[16 + NE] = s;
  }
  __syncthreads();
  for (int i = tid; i < n2; i += (int)blockDim.x) {
    int pos = atomicAdd(&off[te[i]], 1);
    rows_tok[pos] = t0 + (i >> 1);
    rows_wgt[pos] = tw[i];
  }
}

// ---------------- zero fp32 output ----------------
__global__ void zero_kernel(float4* __restrict__ p, int n4) {
  int i = blockIdx.x * blockDim.x + threadIdx.x;
  int st = gridDim.x * blockDim.x;
  float4 z; z.x = z.y = z.z = z.w = 0.f;
  for (; i < n4; i += st) p[i] = z;
}

// ============ up-projection: M256 x N128, BK=64, XOR-swizzled LDS,
// ============ global_load_lds + 2-phase double buffer, 8 waves (4x2).
// 1-D grid with XCD-affinity decode: all m-tiles of a weight panel
// (n-tile, expert) share id%8 -> same XCD -> weight panel L2-resident.
__global__ __launch_bounds__(512, 2)
void ffn_up_kernel(const unsigned short* __restrict__ xb,
                   const unsigned short* __restrict__ wt1,
                   const unsigned short* __restrict__ wt3,
                   const float* __restrict__ bf1, const float* __restrict__ bf3,
                   const int* __restrict__ meta,
                   const int* __restrict__ rows_tok,
                   unsigned short* __restrict__ h_buf,
                   unsigned short* __restrict__ sh_buf,
                   int t0, int TS, int my) {
  const int NX = HH / 128;          // 11 n-tiles
  const int P = NX * (NE + 1);      // 99 panels
  const int id = blockIdx.x;
  const int xcd = id & 7;
  const int rest = id >> 3;
  const int mtile = rest % my;
  const int chunk = rest / my;
  const int panel = chunk * 8 + xcd;
  if (panel >= P) return;
  const int z = panel / NX;
  const int n0 = (panel - z * NX) * 128;

  const bool shx = (z == NE);
  int g0, cnt;
  unsigned short* ho;
  if (shx) { g0 = 0; cnt = TS; ho = sh_buf; }
  else {
    g0 = meta[16 + z]; cnt = meta[17 + z] - g0;
    ho = h_buf + (size_t)g0 * HH;
  }
  if (mtile * 256 >= cnt) return;
  const unsigned short* wa = wt1 + (size_t)z * HH * DD;  // [HH][DD] bf16
  const unsigned short* wb = wt3 + (size_t)z * HH * DD;

  // per buffer: A 256x64 (16384) + B1 128x64 (8192) + B3 128x64 (8192) shorts
  __shared__ alignas(16) unsigned short lds[2 * 32768];

  const int tid = threadIdx.x;
  const int lane = tid & 63, wid = tid >> 6;
  const int rsub = wid * 8 + (lane >> 3);        // row within 64-row chunk
  const int sl8 = (((lane & 7) ^ (lane >> 3)) << 3);  // swizzled source col (elems)

  size_t aoff[4];
#pragma unroll
  for (int c = 0; c < 4; c++) {
    int r = c * 64 + rsub;
    int m = mtile * 256 + r;
    int rr = (m < cnt) ? m : (cnt - 1);
    int srow = shx ? (t0 + rr) : rows_tok[g0 + rr];
    aoff[c] = (size_t)srow * DD + sl8;
  }
  size_t boff[2];
#pragma unroll
  for (int c = 0; c < 2; c++)
    boff[c] = (size_t)(n0 + c * 64 + rsub) * DD + sl8;

  const int ln15 = lane & 15;
  const int lg = lane >> 4;           // 0..3
  const int wr = (wid >> 1) << 6;     // 0,64,128,192
  const int wc = (wid & 1) << 6;      // 0,64
  const int ldsw = wid * 512;

  f32x4 acc1[4][4], acc3[4][4];
#pragma unroll
  for (int a = 0; a < 4; a++)
#pragma unroll
    for (int b = 0; b < 4; b++) {
      acc1[a][b] = {0.f, 0.f, 0.f, 0.f};
      acc3[a][b] = {0.f, 0.f, 0.f, 0.f};
    }

  auto stage = [&](int buf, int k) {
    unsigned short* Lb = &lds[buf * 32768];
#pragma unroll
    for (int c = 0; c < 4; c++)
      gl16(xb + aoff[c] + k, Lb + c * 4096 + ldsw);
#pragma unroll
    for (int c = 0; c < 2; c++) {
      gl16(wa + boff[c] + k, Lb + 16384 + c * 4096 + ldsw);
      gl16(wb + boff[c] + k, Lb + 24576 + c * 4096 + ldsw);
    }
  };

  stage(0, 0);
  const int NT = DD / 64;  // 16
  for (int t = 0; t < NT; ++t) {
    asm volatile("s_waitcnt vmcnt(0)" ::: "memory");
    __syncthreads();
    if (t + 1 < NT) stage((t + 1) & 1, (t + 1) * 64);
    const unsigned short* Lb = &lds[(t & 1) * 32768];
#pragma unroll
    for (int ks = 0; ks < 2; ks++) {
      bf16x8 af[4];
#pragma unroll
      for (int fm = 0; fm < 4; fm++) {
        int R = wr + fm * 16 + ln15;
        af[fm] = *(const bf16x8*)&Lb[R * 64 + ((((ks << 2) | lg) ^ (R & 7)) << 3)];
      }
#pragma unroll
      for (int fn = 0; fn < 4; fn++) {
        int Rb = wc + fn * 16 + ln15;
        int o = Rb * 64 + ((((ks << 2) | lg) ^ (Rb & 7)) << 3);
        bf16x8 b1v = *(const bf16x8*)&Lb[16384 + o];
        bf16x8 b3v = *(const bf16x8*)&Lb[24576 + o];
#pragma unroll
        for (int fm = 0; fm < 4; fm++) {
          acc1[fm][fn] = __builtin_amdgcn_mfma_f32_16x16x32_bf16(af[fm], b1v, acc1[fm][fn], 0, 0, 0);
          acc3[fm][fn] = __builtin_amdgcn_mfma_f32_16x16x32_bf16(af[fm], b3v, acc3[fm][fn], 0, 0, 0);
        }
      }
    }
  }

  const int kq4 = lg << 2;
#pragma unroll
  for (int fm = 0; fm < 4; fm++) {
#pragma unroll
    for (int r = 0; r < 4; r++) {
      int m = mtile * 256 + wr + fm * 16 + kq4 + r;
      if (m < cnt) {
        unsigned short* orow = ho + (size_t)m * HH + n0;
#pragma unroll
        for (int fn = 0; fn < 4; fn++) {
          int nc = wc + fn * 16 + ln15;
          float g1 = acc1[fm][fn][r] + bf1[(size_t)z * HH + n0 + nc];
          float g3 = acc3[fm][fn][r] + bf3[(size_t)z * HH + n0 + nc];
          float u = g1 * g3;
          float hv = u * __builtin_amdgcn_rcpf(1.f + __expf(-u));  // silu(g1*g3)
          orow[nc] = f2bf(hv);
        }
      }
    }
  }
}

// ============ down-projection: M256 x N128, BK=64, same pipeline ============
__global__ __launch_bounds__(512, 2)
void ffn_down_kernel(const unsigned short* __restrict__ h_buf,
                     const unsigned short* __restrict__ sh_buf,
                     const unsigned short* __restrict__ wt2,
                     const float* __restrict__ bf2,
                     const int* __restrict__ meta,
                     const int* __restrict__ rows_tok,
                     const float* __restrict__ rows_wgt,
                     float* __restrict__ out, int t0, int TS, int my) {
  const int NX = DD / 128;          // 8 n-tiles
  const int P = NX * (NE + 1);      // 72 panels (divisible by 8)
  const int id = blockIdx.x;
  const int xcd = id & 7;
  const int rest = id >> 3;
  const int mtile = rest % my;
  const int chunk = rest / my;
  const int panel = chunk * 8 + xcd;
  if (panel >= P) return;
  const int z = panel / NX;
  const int n0 = (panel - z * NX) * 128;

  const bool shx = (z == NE);
  int g0, cnt;
  const unsigned short* hb;
  if (shx) { g0 = 0; cnt = TS; hb = sh_buf; }
  else {
    g0 = meta[16 + z]; cnt = meta[17 + z] - g0;
    hb = h_buf + (size_t)g0 * HH;
  }
  if (mtile * 256 >= cnt) return;
  const unsigned short* ws = wt2 + (size_t)z * DD * HH;  // [DD][HH] bf16

  // per buffer: A 256x64 (16384) + B 128x64 (8192) shorts
  __shared__ alignas(16) unsigned short lds[2 * 24576];

  const int tid = threadIdx.x;
  const int lane = tid & 63, wid = tid >> 6;
  const int rsub = wid * 8 + (lane >> 3);
  const int sl8 = (((lane & 7) ^ (lane >> 3)) << 3);

  size_t aoff[4];
#pragma unroll
  for (int c = 0; c < 4; c++) {
    int r = c * 64 + rsub;
    int m = mtile * 256 + r;
    int rr = (m < cnt) ? m : (cnt - 1);
    aoff[c] = (size_t)rr * HH + sl8;
  }
  size_t boff[2];
#pragma unroll
  for (int c = 0; c < 2; c++)
    boff[c] = (size_t)(n0 + c * 64 + rsub) * HH + sl8;

  const int ln15 = lane & 15;
  const int lg = lane >> 4;
  const int wr = (wid >> 1) << 6;
  const int wc = (wid & 1) << 6;
  const int ldsw = wid * 512;

  f32x4 acc[4][4];
#pragma unroll
  for (int a = 0; a < 4; a++)
#pragma unroll
    for (int b = 0; b < 4; b++) acc[a][b] = {0.f, 0.f, 0.f, 0.f};

  auto stage = [&](int buf, int k) {
    unsigned short* Lb = &lds[buf * 24576];
#pragma unroll
    for (int c = 0; c < 4; c++)
      gl16(hb + aoff[c] + k, Lb + c * 4096 + ldsw);
#pragma unroll
    for (int c = 0; c < 2; c++)
      gl16(ws + boff[c] + k, Lb + 16384 + c * 4096 + ldsw);
  };

  stage(0, 0);
  const int NT = HH / 64;  // 22
  for (int t = 0; t < NT; ++t) {
    asm volatile("s_waitcnt vmcnt(0)" ::: "memory");
    __syncthreads();
    if (t + 1 < NT) stage((t + 1) & 1, (t + 1) * 64);
    const unsigned short* Lb = &lds[(t & 1) * 24576];
#pragma unroll
    for (int ks = 0; ks < 2; ks++) {
      bf16x8 af[4];
#pragma unroll
      for (int fm = 0; fm < 4; fm++) {
        int R = wr + fm * 16 + ln15;
        af[fm] = *(const bf16x8*)&Lb[R * 64 + ((((ks << 2) | lg) ^ (R & 7)) << 3)];
      }
#pragma unroll
      for (int fn = 0; fn < 4; fn++) {
        int Rb = wc + fn * 16 + ln15;
        int o = Rb * 64 + ((((ks << 2) | lg) ^ (Rb & 7)) << 3);
        bf16x8 bv = *(const bf16x8*)&Lb[16384 + o];
#pragma unroll
        for (int fm = 0; fm < 4; fm++)
          acc[fm][fn] = __builtin_amdgcn_mfma_f32_16x16x32_bf16(af[fm], bv, acc[fm][fn], 0, 0, 0);
      }
    }
  }

  const int kq4 = lg << 2;
#pragma unroll
  for (int fm = 0; fm < 4; fm++) {
#pragma unroll
    for (int r4 = 0; r4 < 4; r4++) {
      int m = mtile * 256 + wr + fm * 16 + kq4 + r4;
      if (m < cnt) {
        int t; float wgt;
        if (shx) { t = t0 + m; wgt = 1.f; }
        else { t = rows_tok[g0 + m]; wgt = rows_wgt[g0 + m]; }
        float* orow = out + (size_t)t * DD + n0;
#pragma unroll
        for (int fn = 0; fn < 4; fn++) {
          int nc = wc + fn * 16 + ln15;
          float v = wgt * (acc[fm][fn][r4] + bf2[(size_t)z * DD + n0 + nc]);
          atomicAdd(&orow[nc], v);
        }
      }
    }
  }
}

extern "C" void kernel_launch(void* const* d_in, const int* in_sizes, int n_in,
                              void* d_out, int out_size, void* d_ws, size_t ws_size,
                              hipStream_t stream) {
  const void* x   = d_in[0];
  const void* gw  = d_in[1];
  const void* gb  = d_in[2];
  const void* w1  = d_in[3];
  const void* b1  = d_in[4];
  const void* w3  = d_in[5];
  const void* b3  = d_in[6];
  const void* w2  = d_in[7];
  const void* b2  = d_in[8];
  const void* sw1 = d_in[9];
  const void* sb1 = d_in[10];
  const void* sw3 = d_in[11];
  const void* sb3 = d_in[12];
  const void* sw2 = d_in[13];
  const void* sb2 = d_in[14];

  const int T = in_sizes[0] / DD;  // 4096
  (void)n_in; (void)out_size;

  const size_t WMAT = (size_t)(NE + 1) * HH * DD;

  auto need = [&](int S) -> size_t {
    int TS = T / S;
    size_t o = 0;
    auto pad = [&](size_t b) { o = (o + b + 255) & ~(size_t)255; };
    pad(256);
    pad(32 * sizeof(int));
    pad((size_t)T * 2 * sizeof(int));
    pad((size_t)T * 2 * sizeof(float));
    pad((size_t)T * DD * 2);
    pad(WMAT * 2);
    pad(WMAT * 2);
    pad(WMAT * 2);
    pad((size_t)(NE + 1) * HH * sizeof(float));
    pad((size_t)(NE + 1) * HH * sizeof(float));
    pad((size_t)(NE + 1) * DD * sizeof(float));
    pad((size_t)TS * 2 * sizeof(int));
    pad((size_t)TS * 2 * sizeof(float));
    pad((size_t)TS * 2 * HH * 2);
    pad((size_t)TS * HH * 2);
    return o;
  };
  int S = 32;
  {
    const int cand[6] = {1, 2, 4, 8, 16, 32};
    for (int ci = 0; ci < 6; ci++) {
      if (need(cand[ci]) <= ws_size) { S = cand[ci]; break; }
    }
  }
  const int TS = T / S;
  const int my = (TS + 255) / 256;

  char* w = (char*)d_ws;
  size_t off = 0;
  auto take = [&](size_t bytes) {
    char* p = w + off;
    off = (off + bytes + 255) & ~(size_t)255;
    return p;
  };
  int*   dflag    = (int*)  take(256);
  int*   meta     = (int*)  take(32 * sizeof(int));
  int*   tok_eidx = (int*)  take((size_t)T * 2 * sizeof(int));
  float* tok_w    = (float*)take((size_t)T * 2 * sizeof(float));
  unsigned short* xb  = (unsigned short*)take((size_t)T * DD * 2);
  unsigned short* wt1 = (unsigned short*)take(WMAT * 2);
  unsigned short* wt3 = (unsigned short*)take(WMAT * 2);
  unsigned short* wt2 = (unsigned short*)take(WMAT * 2);
  float* bf1 = (float*)take((size_t)(NE + 1) * HH * sizeof(float));
  float* bf3 = (float*)take((size_t)(NE + 1) * HH * sizeof(float));
  float* bf2 = (float*)take((size_t)(NE + 1) * DD * sizeof(float));
  int*   rows_tok = (int*)  take((size_t)TS * 2 * sizeof(int));
  float* rows_wgt = (float*)take((size_t)TS * 2 * sizeof(float));
  unsigned short* h_buf  = (unsigned short*)take((size_t)TS * 2 * HH * 2);
  unsigned short* sh_buf = (unsigned short*)take((size_t)TS * HH * 2);

  sniff_kernel<<<1, 256, 0, stream>>>((const unsigned short*)x, dflag);

  cvtx_kernel<<<2048, 256, 0, stream>>>(x, dflag, xb, T * DD / 8);
  trans_kernel<<<dim3(HH / 32, DD / 32, NE + 1), 256, 0, stream>>>(w1, sw1, dflag, wt1, DD, HH);
  trans_kernel<<<dim3(HH / 32, DD / 32, NE + 1), 256, 0, stream>>>(w3, sw3, dflag, wt3, DD, HH);
  trans_kernel<<<dim3(DD / 32, HH / 32, NE + 1), 256, 0, stream>>>(w2, sw2, dflag, wt2, HH, DD);
  {
    int nb = (2 * (NE + 1) * HH + (NE + 1) * DD + 255) / 256;
    cvtb_kernel<<<nb, 256, 0, stream>>>(b1, b3, b2, sb1, sb3, sb2, dflag, bf1, bf3, bf2);
  }

  gate_kernel<<<(T + 3) / 4, 256, 0, stream>>>(x, gw, gb, dflag, tok_eidx, tok_w, T);
  zero_kernel<<<1024, 256, 0, stream>>>((float4*)d_out, T * DD / 4);

  // XCD-affinity 1-D grids: 8 * ceil(P/8) * my
  const int upP = (HH / 128) * (NE + 1);    // 99
  const int dnP = (DD / 128) * (NE + 1);    // 72
  const int upGrid = 8 * ((upP + 7) / 8) * my;
  const int dnGrid = 8 * ((dnP + 7) / 8) * my;

  for (int s = 0; s < S; s++) {
    const int t0 = s * TS;
    prep_kernel<<<1, 1024, 0, stream>>>(tok_eidx, tok_w, meta, rows_tok, rows_wgt, t0, TS);
    ffn_up_kernel<<<upGrid, 512, 0, stream>>>(
        xb, wt1, wt3, bf1, bf3, meta, rows_tok, h_buf, sh_buf, t0, TS, my);
    ffn_down_kernel<<<dnGrid, 512, 0, stream>>>(
        h_buf, sh_buf, wt2, bf2, meta, rows_tok, rows_wgt, (float*)d_out, t0, TS, my);
  }
}

// Round 5
// 454.521 us; speedup vs baseline: 1.0027x; 1.0027x over previous
//
#include <hip/hip_runtime.h>
#include <math.h>

#define DD 1024   // hidden dim
#define HH 1408   // moe inter dim
#define NE 8      // experts

typedef __attribute__((ext_vector_type(8))) __bf16 bf16x8;
typedef __attribute__((ext_vector_type(4))) float f32x4;

__device__ __forceinline__ float bf2f(unsigned short u) {
  union { unsigned int i; float f; } v; v.i = ((unsigned int)u) << 16; return v.f;
}
__device__ __forceinline__ unsigned short f2bf(float f) {
  union { float f; unsigned int i; } v; v.f = f;
  unsigned int r = v.i + 0x7FFFu + ((v.i >> 16) & 1u);  // RNE
  return (unsigned short)(r >> 16);
}
__device__ __forceinline__ float tof(float f) { return f; }
__device__ __forceinline__ float tof(unsigned short u) { return bf2f(u); }

// pack bf16(a) | bf16(b)<<16 in ONE instruction (RNE, gfx950)
__device__ __forceinline__ void cvt2(float a, float b, unsigned int* o) {
  asm("v_cvt_pk_bf16_f32 %0, %1, %2" : "=v"(*o) : "v"(a), "v"(b));
}

__device__ __forceinline__ void ld8cvt(const float* p, unsigned int* o) {
  float4 a = *(const float4*)p;
  float4 b = *(const float4*)(p + 4);
  cvt2(a.x, a.y, o + 0); cvt2(a.z, a.w, o + 1);
  cvt2(b.x, b.y, o + 2); cvt2(b.z, b.w, o + 3);
}

// async global->LDS, 16 bytes per lane; LDS dest must be wave-uniform base
typedef unsigned int __attribute__((address_space(1))) gu32;
typedef unsigned int __attribute__((address_space(3))) lu32;
__device__ __forceinline__ void gl16(const unsigned short* g, unsigned short* l) {
  __builtin_amdgcn_global_load_lds((const gu32*)g, (lu32*)l, 16, 0, 0);
}

// ---------------- sniff input dtype: 1 = fp32, 0 = bf16 ----------------
__global__ void sniff_kernel(const unsigned short* __restrict__ xw,
                             int* __restrict__ dflag) {
  __shared__ int cnt;
  if (threadIdx.x == 0) cnt = 0;
  __syncthreads();
  unsigned short v = xw[threadIdx.x];
  int e = (v >> 7) & 0xFF;
  if (e >= 100 && e <= 140) atomicAdd(&cnt, 1);
  __syncthreads();
  if (threadIdx.x == 0) dflag[0] = (cnt < 230) ? 1 : 0;
}

// ---------------- convert x -> bf16 ----------------
__global__ void cvtx_kernel(const void* __restrict__ x,
                            const int* __restrict__ dflag,
                            unsigned short* __restrict__ xb, int n8) {
  int i = blockIdx.x * blockDim.x + threadIdx.x;
  int st = gridDim.x * blockDim.x;
  if (dflag[0]) {
    const float* xs = (const float*)x;
    for (; i < n8; i += st) {
      unsigned int o[4];
      ld8cvt(xs + (size_t)i * 8, o);
      *(uint4*)(xb + (size_t)i * 8) = *(uint4*)o;
    }
  } else {
    const uint4* xs = (const uint4*)x;
    for (; i < n8; i += st) *(uint4*)(xb + (size_t)i * 8) = xs[i];
  }
}

// ---------------- transpose+convert weights: [mat][R][C] -> [mat][C][R] bf16 ----
__global__ void trans_kernel(const void* __restrict__ wmain,
                             const void* __restrict__ wsh,
                             const int* __restrict__ dflag,
                             unsigned short* __restrict__ out, int R, int C) {
  __shared__ float tile[32][33];
  const int mat = blockIdx.z;
  const int r0 = blockIdx.y << 5, c0 = blockIdx.x << 5;
  const int t = threadIdx.x;                 // 256 threads
  const int lr = t >> 3, lc = (t & 7) << 2;
  const size_t mbase = (size_t)mat * R * C;
  if (dflag[0]) {
    const float* src = (mat < NE) ? ((const float*)wmain + mbase) : (const float*)wsh;
    float4 v = *(const float4*)(src + (size_t)(r0 + lr) * C + c0 + lc);
    tile[lr][lc] = v.x; tile[lr][lc + 1] = v.y;
    tile[lr][lc + 2] = v.z; tile[lr][lc + 3] = v.w;
  } else {
    const unsigned short* src = (mat < NE) ? ((const unsigned short*)wmain + mbase)
                                           : (const unsigned short*)wsh;
    ushort4 v = *(const ushort4*)(src + (size_t)(r0 + lr) * C + c0 + lc);
    tile[lr][lc] = bf2f(v.x); tile[lr][lc + 1] = bf2f(v.y);
    tile[lr][lc + 2] = bf2f(v.z); tile[lr][lc + 3] = bf2f(v.w);
  }
  __syncthreads();
  const int oc = t >> 3;
  const int orr = (t & 7) << 2;
  unsigned int p0, p1;
  cvt2(tile[orr][oc], tile[orr + 1][oc], &p0);
  cvt2(tile[orr + 2][oc], tile[orr + 3][oc], &p1);
  uint2 pk; pk.x = p0; pk.y = p1;
  *(uint2*)(out + mbase + (size_t)(c0 + oc) * R + r0 + orr) = pk;
}

// ---------------- biases -> f32, [NE+1] stacked (slot NE = shared) ----------
__global__ void cvtb_kernel(const void* b1, const void* b3, const void* b2,
                            const void* sb1, const void* sb3, const void* sb2,
                            const int* __restrict__ dflag,
                            float* __restrict__ bf1, float* __restrict__ bf3,
                            float* __restrict__ bf2o) {
  int i = blockIdx.x * blockDim.x + threadIdx.x;
  const int nh = (NE + 1) * HH, nd = (NE + 1) * DD;
  const bool f32 = dflag[0] != 0;
  auto get = [&](const void* pm, const void* ps, int idx, int per) -> float {
    int mat = idx / per, j = idx - mat * per;
    if (f32) return (mat < NE) ? ((const float*)pm)[(size_t)mat * per + j]
                               : ((const float*)ps)[j];
    return bf2f((mat < NE) ? ((const unsigned short*)pm)[(size_t)mat * per + j]
                           : ((const unsigned short*)ps)[j]);
  };
  if (i < nh) bf1[i] = get(b1, sb1, i, HH);
  else if (i < 2 * nh) bf3[i - nh] = get(b3, sb3, i - nh, HH);
  else if (i < 2 * nh + nd) bf2o[i - 2 * nh] = get(b2, sb2, i - 2 * nh, DD);
}

// ---------------- gate: one wave per token ----------------
template <class T>
__device__ void gate_body(const T* __restrict__ x,
                          const T* __restrict__ gw,
                          const T* __restrict__ gb,
                          int* __restrict__ tok_eidx,
                          float* __restrict__ tok_w, int T_) {
  int t = (int)((blockIdx.x * blockDim.x + threadIdx.x) >> 6);
  int lane = threadIdx.x & 63;
  if (t >= T_) return;
  const T* xr = x + (size_t)t * DD;
  float acc[NE];
#pragma unroll
  for (int e = 0; e < NE; e++) acc[e] = 0.f;
  for (int i = lane; i < DD; i += 64) {
    float xv = tof(xr[i]);
#pragma unroll
    for (int e = 0; e < NE; e++) acc[e] += xv * tof(gw[e * DD + i]);
  }
#pragma unroll
  for (int off = 32; off > 0; off >>= 1) {
#pragma unroll
    for (int e = 0; e < NE; e++) acc[e] += __shfl_xor(acc[e], off);
  }
  if (lane == 0) {
    float mx = acc[0];
#pragma unroll
    for (int e = 1; e < NE; e++) mx = fmaxf(mx, acc[e]);
    float s = 0.f, sc[NE], bi[NE];
#pragma unroll
    for (int e = 0; e < NE; e++) { sc[e] = expf(acc[e] - mx); s += sc[e]; }
    float inv = 1.f / s;
#pragma unroll
    for (int e = 0; e < NE; e++) { sc[e] *= inv; bi[e] = sc[e] + tof(gb[e]); }
    int i1 = 0;
#pragma unroll
    for (int e = 1; e < NE; e++) if (bi[e] > bi[i1]) i1 = e;
    int i2 = (i1 == 0) ? 1 : 0;
#pragma unroll
    for (int e = 0; e < NE; e++) if (e != i1 && bi[e] > bi[i2]) i2 = e;
    tok_eidx[t * 2] = i1; tok_eidx[t * 2 + 1] = i2;
    tok_w[t * 2] = sc[i1]; tok_w[t * 2 + 1] = sc[i2];
  }
}

__global__ void gate_kernel(const void* x, const void* gw, const void* gb,
                            const int* __restrict__ dflag,
                            int* tok_eidx, float* tok_w, int T_) {
  if (dflag[0])
    gate_body<float>((const float*)x, (const float*)gw, (const float*)gb,
                     tok_eidx, tok_w, T_);
  else
    gate_body<unsigned short>((const unsigned short*)x, (const unsigned short*)gw,
                              (const unsigned short*)gb, tok_eidx, tok_w, T_);
}

// ------- fused count + scan + scatter (single block); also records pos -------
__global__ void prep_kernel(const int* __restrict__ tok_eidx,
                            const float* __restrict__ tok_w,
                            int* __restrict__ meta,
                            int* __restrict__ rows_tok,
                            float* __restrict__ rows_wgt,
                            int* __restrict__ tok_pos,
                            int t0, int TS) {
  __shared__ int cnt[NE];
  __shared__ int off[NE];
  const int tid = threadIdx.x;
  if (tid < NE) cnt[tid] = 0;
  __syncthreads();
  const int n2 = TS * 2;
  const int* te = tok_eidx + (size_t)t0 * 2;
  const float* tw = tok_w + (size_t)t0 * 2;
  for (int i = tid; i < n2; i += (int)blockDim.x) atomicAdd(&cnt[te[i]], 1);
  __syncthreads();
  if (tid == 0) {
    int s = 0;
#pragma unroll
    for (int e = 0; e < NE; e++) { off[e] = s; meta[16 + e] = s; s += cnt[e]; }
    meta[16 + NE] = s;
  }
  __syncthreads();
  for (int i = tid; i < n2; i += (int)blockDim.x) {
    int pos = atomicAdd(&off[te[i]], 1);
    rows_tok[pos] = t0 + (i >> 1);
    rows_wgt[pos] = tw[i];
    tok_pos[(size_t)(t0 + (i >> 1)) * 2 + (i & 1)] = pos;
  }
}

// ---------------- combine: d_out[t] += r_out[pos0] + r_out[pos1] ----------
__global__ void combine_kernel(const float4* __restrict__ r_out,
                               const int* __restrict__ tok_pos,
                               float4* __restrict__ out, int t0, int TS) {
  const int C4 = DD / 4;
  int i = blockIdx.x * blockDim.x + threadIdx.x;
  int n4 = TS * C4;
  int st = gridDim.x * blockDim.x;
  for (; i < n4; i += st) {
    int tl = i / C4, c = i - tl * C4;
    int t = t0 + tl;
    int p0 = tok_pos[t * 2], p1 = tok_pos[t * 2 + 1];
    float4 a = out[(size_t)t * C4 + c];
    float4 b = r_out[(size_t)p0 * C4 + c];
    float4 d = r_out[(size_t)p1 * C4 + c];
    a.x += b.x + d.x; a.y += b.y + d.y;
    a.z += b.z + d.z; a.w += b.w + d.w;
    out[(size_t)t * C4 + c] = a;
  }
}

// ============ up-projection: M256 x N128, BK=64, XOR-swizzled LDS,
// ============ global_load_lds + counted-vmcnt 2-deep pipeline, 8 waves.
// XCD-affinity decode: all m-tiles of a panel share id%8 -> same XCD L2.
__global__ __launch_bounds__(512, 2)
void ffn_up_kernel(const unsigned short* __restrict__ xb,
                   const unsigned short* __restrict__ wt1,
                   const unsigned short* __restrict__ wt3,
                   const float* __restrict__ bf1, const float* __restrict__ bf3,
                   const int* __restrict__ meta,
                   const int* __restrict__ rows_tok,
                   unsigned short* __restrict__ h_buf,
                   unsigned short* __restrict__ sh_buf,
                   int t0, int TS, int my) {
  const int NX = HH / 128;          // 11 n-tiles
  const int P = NX * (NE + 1);      // 99 panels
  const int id = blockIdx.x;
  const int xcd = id & 7;
  const int rest = id >> 3;
  const int mtile = rest % my;
  const int chunk = rest / my;
  const int panel = chunk * 8 + xcd;
  if (panel >= P) return;
  const int z = panel / NX;
  const int n0 = (panel - z * NX) * 128;

  const bool shx = (z == NE);
  int g0, cnt;
  unsigned short* ho;
  if (shx) { g0 = 0; cnt = TS; ho = sh_buf; }
  else {
    g0 = meta[16 + z]; cnt = meta[17 + z] - g0;
    ho = h_buf + (size_t)g0 * HH;
  }
  if (mtile * 256 >= cnt) return;
  const unsigned short* wa = wt1 + (size_t)z * HH * DD;  // [HH][DD] bf16
  const unsigned short* wb = wt3 + (size_t)z * HH * DD;

  // per buffer: A 256x64 (16384) + B1 128x64 (8192) + B3 128x64 (8192) shorts
  __shared__ alignas(16) unsigned short lds[2 * 32768];

  const int tid = threadIdx.x;
  const int lane = tid & 63, wid = tid >> 6;
  const int rsub = wid * 8 + (lane >> 3);        // row within 64-row chunk
  const int sl8 = (((lane & 7) ^ (lane >> 3)) << 3);  // swizzled source col

  size_t aoff[4];
#pragma unroll
  for (int c = 0; c < 4; c++) {
    int r = c * 64 + rsub;
    int m = mtile * 256 + r;
    int rr = (m < cnt) ? m : (cnt - 1);
    int srow = shx ? (t0 + rr) : rows_tok[g0 + rr];
    aoff[c] = (size_t)srow * DD + sl8;
  }
  size_t boff[2];
#pragma unroll
  for (int c = 0; c < 2; c++)
    boff[c] = (size_t)(n0 + c * 64 + rsub) * DD + sl8;

  const int ln15 = lane & 15;
  const int lg = lane >> 4;           // 0..3
  const int wr = (wid >> 1) << 6;     // 0,64,128,192
  const int wc = (wid & 1) << 6;      // 0,64
  const int ldsw = wid * 512;

  f32x4 acc1[4][4], acc3[4][4];
#pragma unroll
  for (int a = 0; a < 4; a++)
#pragma unroll
    for (int b = 0; b < 4; b++) {
      acc1[a][b] = {0.f, 0.f, 0.f, 0.f};
      acc3[a][b] = {0.f, 0.f, 0.f, 0.f};
    }

  auto stage = [&](int buf, int k) {  // 8 gl16 per thread
    unsigned short* Lb = &lds[buf * 32768];
#pragma unroll
    for (int c = 0; c < 4; c++)
      gl16(xb + aoff[c] + k, Lb + c * 4096 + ldsw);
#pragma unroll
    for (int c = 0; c < 2; c++) {
      gl16(wa + boff[c] + k, Lb + 16384 + c * 4096 + ldsw);
      gl16(wb + boff[c] + k, Lb + 24576 + c * 4096 + ldsw);
    }
  };

  stage(0, 0);
  const int NT = DD / 64;  // 16
  for (int t = 0; t < NT; ++t) {
    if (t + 1 < NT) {
      stage((t + 1) & 1, (t + 1) * 64);   // keep 8 loads in flight
      asm volatile("s_waitcnt vmcnt(8)" ::: "memory");
    } else {
      asm volatile("s_waitcnt vmcnt(0)" ::: "memory");
    }
    __builtin_amdgcn_sched_barrier(0);
    __builtin_amdgcn_s_barrier();        // raw: no implicit drain
    __builtin_amdgcn_sched_barrier(0);
    const unsigned short* Lb = &lds[(t & 1) * 32768];
    __builtin_amdgcn_s_setprio(1);
#pragma unroll
    for (int ks = 0; ks < 2; ks++) {
      bf16x8 af[4];
#pragma unroll
      for (int fm = 0; fm < 4; fm++) {
        int R = wr + fm * 16 + ln15;
        af[fm] = *(const bf16x8*)&Lb[R * 64 + ((((ks << 2) | lg) ^ (R & 7)) << 3)];
      }
#pragma unroll
      for (int fn = 0; fn < 4; fn++) {
        int Rb = wc + fn * 16 + ln15;
        int o = Rb * 64 + ((((ks << 2) | lg) ^ (Rb & 7)) << 3);
        bf16x8 b1v = *(const bf16x8*)&Lb[16384 + o];
        bf16x8 b3v = *(const bf16x8*)&Lb[24576 + o];
#pragma unroll
        for (int fm = 0; fm < 4; fm++) {
          acc1[fm][fn] = __builtin_amdgcn_mfma_f32_16x16x32_bf16(af[fm], b1v, acc1[fm][fn], 0, 0, 0);
          acc3[fm][fn] = __builtin_amdgcn_mfma_f32_16x16x32_bf16(af[fm], b3v, acc3[fm][fn], 0, 0, 0);
        }
      }
    }
    __builtin_amdgcn_s_setprio(0);
    asm volatile("s_waitcnt lgkmcnt(0)" ::: "memory");
    __builtin_amdgcn_sched_barrier(0);
    __builtin_amdgcn_s_barrier();        // all waves done reading buf[t&1]
    __builtin_amdgcn_sched_barrier(0);
  }

  const int kq4 = lg << 2;
#pragma unroll
  for (int fm = 0; fm < 4; fm++) {
#pragma unroll
    for (int r = 0; r < 4; r++) {
      int m = mtile * 256 + wr + fm * 16 + kq4 + r;
      if (m < cnt) {
        unsigned short* orow = ho + (size_t)m * HH + n0;
#pragma unroll
        for (int fn = 0; fn < 4; fn++) {
          int nc = wc + fn * 16 + ln15;
          float g1 = acc1[fm][fn][r] + bf1[(size_t)z * HH + n0 + nc];
          float g3 = acc3[fm][fn][r] + bf3[(size_t)z * HH + n0 + nc];
          float u = g1 * g3;
          float hv = u * __builtin_amdgcn_rcpf(1.f + __expf(-u));  // silu(g1*g3)
          orow[nc] = f2bf(hv);
        }
      }
    }
  }
}

// ============ down-projection: M256 x N128, BK=64, counted-vmcnt pipeline.
// Routed rows -> r_out (plain stores); shared rows -> d_out directly.
__global__ __launch_bounds__(512, 2)
void ffn_down_kernel(const unsigned short* __restrict__ h_buf,
                     const unsigned short* __restrict__ sh_buf,
                     const unsigned short* __restrict__ wt2,
                     const float* __restrict__ bf2,
                     const int* __restrict__ meta,
                     const int* __restrict__ rows_tok,
                     const float* __restrict__ rows_wgt,
                     float* __restrict__ r_out,
                     float* __restrict__ out, int t0, int TS, int my) {
  const int NX = DD / 128;          // 8 n-tiles
  const int P = NX * (NE + 1);      // 72 panels
  const int id = blockIdx.x;
  const int xcd = id & 7;
  const int rest = id >> 3;
  const int mtile = rest % my;
  const int chunk = rest / my;
  const int panel = chunk * 8 + xcd;
  if (panel >= P) return;
  const int z = panel / NX;
  const int n0 = (panel - z * NX) * 128;

  const bool shx = (z == NE);
  int g0, cnt;
  const unsigned short* hb;
  if (shx) { g0 = 0; cnt = TS; hb = sh_buf; }
  else {
    g0 = meta[16 + z]; cnt = meta[17 + z] - g0;
    hb = h_buf + (size_t)g0 * HH;
  }
  if (mtile * 256 >= cnt) return;
  const unsigned short* ws = wt2 + (size_t)z * DD * HH;  // [DD][HH] bf16

  // per buffer: A 256x64 (16384) + B 128x64 (8192) shorts
  __shared__ alignas(16) unsigned short lds[2 * 24576];

  const int tid = threadIdx.x;
  const int lane = tid & 63, wid = tid >> 6;
  const int rsub = wid * 8 + (lane >> 3);
  const int sl8 = (((lane & 7) ^ (lane >> 3)) << 3);

  size_t aoff[4];
#pragma unroll
  for (int c = 0; c < 4; c++) {
    int r = c * 64 + rsub;
    int m = mtile * 256 + r;
    int rr = (m < cnt) ? m : (cnt - 1);
    aoff[c] = (size_t)rr * HH + sl8;
  }
  size_t boff[2];
#pragma unroll
  for (int c = 0; c < 2; c++)
    boff[c] = (size_t)(n0 + c * 64 + rsub) * HH + sl8;

  const int ln15 = lane & 15;
  const int lg = lane >> 4;
  const int wr = (wid >> 1) << 6;
  const int wc = (wid & 1) << 6;
  const int ldsw = wid * 512;

  f32x4 acc[4][4];
#pragma unroll
  for (int a = 0; a < 4; a++)
#pragma unroll
    for (int b = 0; b < 4; b++) acc[a][b] = {0.f, 0.f, 0.f, 0.f};

  auto stage = [&](int buf, int k) {  // 6 gl16 per thread
    unsigned short* Lb = &lds[buf * 24576];
#pragma unroll
    for (int c = 0; c < 4; c++)
      gl16(hb + aoff[c] + k, Lb + c * 4096 + ldsw);
#pragma unroll
    for (int c = 0; c < 2; c++)
      gl16(ws + boff[c] + k, Lb + 16384 + c * 4096 + ldsw);
  };

  stage(0, 0);
  const int NT = HH / 64;  // 22
  for (int t = 0; t < NT; ++t) {
    if (t + 1 < NT) {
      stage((t + 1) & 1, (t + 1) * 64);
      asm volatile("s_waitcnt vmcnt(6)" ::: "memory");
    } else {
      asm volatile("s_waitcnt vmcnt(0)" ::: "memory");
    }
    __builtin_amdgcn_sched_barrier(0);
    __builtin_amdgcn_s_barrier();
    __builtin_amdgcn_sched_barrier(0);
    const unsigned short* Lb = &lds[(t & 1) * 24576];
    __builtin_amdgcn_s_setprio(1);
#pragma unroll
    for (int ks = 0; ks < 2; ks++) {
      bf16x8 af[4];
#pragma unroll
      for (int fm = 0; fm < 4; fm++) {
        int R = wr + fm * 16 + ln15;
        af[fm] = *(const bf16x8*)&Lb[R * 64 + ((((ks << 2) | lg) ^ (R & 7)) << 3)];
      }
#pragma unroll
      for (int fn = 0; fn < 4; fn++) {
        int Rb = wc + fn * 16 + ln15;
        int o = Rb * 64 + ((((ks << 2) | lg) ^ (Rb & 7)) << 3);
        bf16x8 bv = *(const bf16x8*)&Lb[16384 + o];
#pragma unroll
        for (int fm = 0; fm < 4; fm++)
          acc[fm][fn] = __builtin_amdgcn_mfma_f32_16x16x32_bf16(af[fm], bv, acc[fm][fn], 0, 0, 0);
      }
    }
    __builtin_amdgcn_s_setprio(0);
    asm volatile("s_waitcnt lgkmcnt(0)" ::: "memory");
    __builtin_amdgcn_sched_barrier(0);
    __builtin_amdgcn_s_barrier();
    __builtin_amdgcn_sched_barrier(0);
  }

  const int kq4 = lg << 2;
#pragma unroll
  for (int fm = 0; fm < 4; fm++) {
#pragma unroll
    for (int r4 = 0; r4 < 4; r4++) {
      int m = mtile * 256 + wr + fm * 16 + kq4 + r4;
      if (m < cnt) {
        float* orow;
        float wgt;
        if (shx) { orow = out + (size_t)(t0 + m) * DD + n0; wgt = 1.f; }
        else { orow = r_out + (size_t)(g0 + m) * DD + n0; wgt = rows_wgt[g0 + m]; }
#pragma unroll
        for (int fn = 0; fn < 4; fn++) {
          int nc = wc + fn * 16 + ln15;
          orow[nc] = wgt * (acc[fm][fn][r4] + bf2[(size_t)z * DD + n0 + nc]);
        }
      }
    }
  }
}

extern "C" void kernel_launch(void* const* d_in, const int* in_sizes, int n_in,
                              void* d_out, int out_size, void* d_ws, size_t ws_size,
                              hipStream_t stream) {
  const void* x   = d_in[0];
  const void* gw  = d_in[1];
  const void* gb  = d_in[2];
  const void* w1  = d_in[3];
  const void* b1  = d_in[4];
  const void* w3  = d_in[5];
  const void* b3  = d_in[6];
  const void* w2  = d_in[7];
  const void* b2  = d_in[8];
  const void* sw1 = d_in[9];
  const void* sb1 = d_in[10];
  const void* sw3 = d_in[11];
  const void* sb3 = d_in[12];
  const void* sw2 = d_in[13];
  const void* sb2 = d_in[14];

  const int T = in_sizes[0] / DD;  // 4096
  (void)n_in; (void)out_size;

  const size_t WMAT = (size_t)(NE + 1) * HH * DD;

  auto need = [&](int S) -> size_t {
    int TS = T / S;
    size_t o = 0;
    auto pad = [&](size_t b) { o = (o + b + 255) & ~(size_t)255; };
    pad(256);
    pad(32 * sizeof(int));
    pad((size_t)T * 2 * sizeof(int));        // tok_eidx
    pad((size_t)T * 2 * sizeof(float));      // tok_w
    pad((size_t)T * 2 * sizeof(int));        // tok_pos
    pad((size_t)T * DD * 2);                 // xb
    pad(WMAT * 2);
    pad(WMAT * 2);
    pad(WMAT * 2);
    pad((size_t)(NE + 1) * HH * sizeof(float));
    pad((size_t)(NE + 1) * HH * sizeof(float));
    pad((size_t)(NE + 1) * DD * sizeof(float));
    pad((size_t)TS * 2 * sizeof(int));       // rows_tok
    pad((size_t)TS * 2 * sizeof(float));     // rows_wgt
    pad((size_t)TS * 2 * HH * 2);            // h_buf
    pad((size_t)TS * HH * 2);                // sh_buf
    pad((size_t)TS * 2 * DD * sizeof(float)); // r_out
    return o;
  };
  int S = 32;
  {
    const int cand[6] = {1, 2, 4, 8, 16, 32};
    for (int ci = 0; ci < 6; ci++) {
      if (need(cand[ci]) <= ws_size) { S = cand[ci]; break; }
    }
  }
  const int TS = T / S;
  const int my = (TS + 255) / 256;

  char* w = (char*)d_ws;
  size_t off = 0;
  auto take = [&](size_t bytes) {
    char* p = w + off;
    off = (off + bytes + 255) & ~(size_t)255;
    return p;
  };
  int*   dflag    = (int*)  take(256);
  int*   meta     = (int*)  take(32 * sizeof(int));
  int*   tok_eidx = (int*)  take((size_t)T * 2 * sizeof(int));
  float* tok_w    = (float*)take((size_t)T * 2 * sizeof(float));
  int*   tok_pos  = (int*)  take((size_t)T * 2 * sizeof(int));
  unsigned short* xb  = (unsigned short*)take((size_t)T * DD * 2);
  unsigned short* wt1 = (unsigned short*)take(WMAT * 2);
  unsigned short* wt3 = (unsigned short*)take(WMAT * 2);
  unsigned short* wt2 = (unsigned short*)take(WMAT * 2);
  float* bf1 = (float*)take((size_t)(NE + 1) * HH * sizeof(float));
  float* bf3 = (float*)take((size_t)(NE + 1) * HH * sizeof(float));
  float* bf2 = (float*)take((size_t)(NE + 1) * DD * sizeof(float));
  int*   rows_tok = (int*)  take((size_t)TS * 2 * sizeof(int));
  float* rows_wgt = (float*)take((size_t)TS * 2 * sizeof(float));
  unsigned short* h_buf  = (unsigned short*)take((size_t)TS * 2 * HH * 2);
  unsigned short* sh_buf = (unsigned short*)take((size_t)TS * HH * 2);
  float* r_out = (float*)take((size_t)TS * 2 * DD * sizeof(float));

  sniff_kernel<<<1, 256, 0, stream>>>((const unsigned short*)x, dflag);

  cvtx_kernel<<<2048, 256, 0, stream>>>(x, dflag, xb, T * DD / 8);
  trans_kernel<<<dim3(HH / 32, DD / 32, NE + 1), 256, 0, stream>>>(w1, sw1, dflag, wt1, DD, HH);
  trans_kernel<<<dim3(HH / 32, DD / 32, NE + 1), 256, 0, stream>>>(w3, sw3, dflag, wt3, DD, HH);
  trans_kernel<<<dim3(DD / 32, HH / 32, NE + 1), 256, 0, stream>>>(w2, sw2, dflag, wt2, HH, DD);
  {
    int nb = (2 * (NE + 1) * HH + (NE + 1) * DD + 255) / 256;
    cvtb_kernel<<<nb, 256, 0, stream>>>(b1, b3, b2, sb1, sb3, sb2, dflag, bf1, bf3, bf2);
  }

  gate_kernel<<<(T + 3) / 4, 256, 0, stream>>>(x, gw, gb, dflag, tok_eidx, tok_w, T);

  // XCD-affinity 1-D grids
  const int upP = (HH / 128) * (NE + 1);    // 99
  const int dnP = (DD / 128) * (NE + 1);    // 72
  const int upGrid = 8 * ((upP + 7) / 8) * my;
  const int dnGrid = 8 * ((dnP + 7) / 8) * my;

  for (int s = 0; s < S; s++) {
    const int t0 = s * TS;
    prep_kernel<<<1, 1024, 0, stream>>>(tok_eidx, tok_w, meta, rows_tok, rows_wgt,
                                        tok_pos, t0, TS);
    ffn_up_kernel<<<upGrid, 512, 0, stream>>>(
        xb, wt1, wt3, bf1, bf3, meta, rows_tok, h_buf, sh_buf, t0, TS, my);
    ffn_down_kernel<<<dnGrid, 512, 0, stream>>>(
        h_buf, sh_buf, wt2, bf2, meta, rows_tok, rows_wgt, r_out,
        (float*)d_out, t0, TS, my);
    combine_kernel<<<1024, 256, 0, stream>>>((const float4*)r_out, tok_pos,
                                             (float4*)d_out, t0, TS);
  }
}

// Round 6
// 440.076 us; speedup vs baseline: 1.0356x; 1.0328x over previous
//
#include <hip/hip_runtime.h>
#include <math.h>

#define DD 1024   // hidden dim
#define HH 1408   // moe inter dim
#define NE 8      // experts

typedef __attribute__((ext_vector_type(8))) __bf16 bf16x8;
typedef __attribute__((ext_vector_type(4))) float f32x4;

__device__ __forceinline__ float bf2f(unsigned short u) {
  union { unsigned int i; float f; } v; v.i = ((unsigned int)u) << 16; return v.f;
}
__device__ __forceinline__ unsigned short f2bf(float f) {
  union { float f; unsigned int i; } v; v.f = f;
  unsigned int r = v.i + 0x7FFFu + ((v.i >> 16) & 1u);  // RNE
  return (unsigned short)(r >> 16);
}
__device__ __forceinline__ float tof(float f) { return f; }
__device__ __forceinline__ float tof(unsigned short u) { return bf2f(u); }

// pack bf16(a) | bf16(b)<<16 in ONE instruction (RNE, gfx950)
__device__ __forceinline__ void cvt2(float a, float b, unsigned int* o) {
  asm("v_cvt_pk_bf16_f32 %0, %1, %2" : "=v"(*o) : "v"(a), "v"(b));
}

__device__ __forceinline__ void ld8cvt(const float* p, unsigned int* o) {
  float4 a = *(const float4*)p;
  float4 b = *(const float4*)(p + 4);
  cvt2(a.x, a.y, o + 0); cvt2(a.z, a.w, o + 1);
  cvt2(b.x, b.y, o + 2); cvt2(b.z, b.w, o + 3);
}

// async global->LDS, 16 bytes per lane; LDS ptr must be wave-uniform base
// (HW adds lane*16 itself)
typedef unsigned int __attribute__((address_space(1))) gu32;
typedef unsigned int __attribute__((address_space(3))) lu32;
__device__ __forceinline__ void gl16(const unsigned short* g, unsigned short* l) {
  __builtin_amdgcn_global_load_lds((const gu32*)g, (lu32*)l, 16, 0, 0);
}

// ---------------- sniff input dtype: 1 = fp32, 0 = bf16 ----------------
__global__ void sniff_kernel(const unsigned short* __restrict__ xw,
                             int* __restrict__ dflag) {
  __shared__ int cnt;
  if (threadIdx.x == 0) cnt = 0;
  __syncthreads();
  unsigned short v = xw[threadIdx.x];
  int e = (v >> 7) & 0xFF;
  if (e >= 100 && e <= 140) atomicAdd(&cnt, 1);
  __syncthreads();
  if (threadIdx.x == 0) dflag[0] = (cnt < 230) ? 1 : 0;
}

// ---------------- convert x -> bf16 ----------------
__global__ void cvtx_kernel(const void* __restrict__ x,
                            const int* __restrict__ dflag,
                            unsigned short* __restrict__ xb, int n8) {
  int i = blockIdx.x * blockDim.x + threadIdx.x;
  int st = gridDim.x * blockDim.x;
  if (dflag[0]) {
    const float* xs = (const float*)x;
    for (; i < n8; i += st) {
      unsigned int o[4];
      ld8cvt(xs + (size_t)i * 8, o);
      *(uint4*)(xb + (size_t)i * 8) = *(uint4*)o;
    }
  } else {
    const uint4* xs = (const uint4*)x;
    for (; i < n8; i += st) *(uint4*)(xb + (size_t)i * 8) = xs[i];
  }
}

// ---------------- transpose+convert weights: [mat][R][C] -> [mat][C][R] bf16 ----
__global__ void trans_kernel(const void* __restrict__ wmain,
                             const void* __restrict__ wsh,
                             const int* __restrict__ dflag,
                             unsigned short* __restrict__ out, int R, int C) {
  __shared__ float tile[32][33];
  const int mat = blockIdx.z;
  const int r0 = blockIdx.y << 5, c0 = blockIdx.x << 5;
  const int t = threadIdx.x;                 // 256 threads
  const int lr = t >> 3, lc = (t & 7) << 2;
  const size_t mbase = (size_t)mat * R * C;
  if (dflag[0]) {
    const float* src = (mat < NE) ? ((const float*)wmain + mbase) : (const float*)wsh;
    float4 v = *(const float4*)(src + (size_t)(r0 + lr) * C + c0 + lc);
    tile[lr][lc] = v.x; tile[lr][lc + 1] = v.y;
    tile[lr][lc + 2] = v.z; tile[lr][lc + 3] = v.w;
  } else {
    const unsigned short* src = (mat < NE) ? ((const unsigned short*)wmain + mbase)
                                           : (const unsigned short*)wsh;
    ushort4 v = *(const ushort4*)(src + (size_t)(r0 + lr) * C + c0 + lc);
    tile[lr][lc] = bf2f(v.x); tile[lr][lc + 1] = bf2f(v.y);
    tile[lr][lc + 2] = bf2f(v.z); tile[lr][lc + 3] = bf2f(v.w);
  }
  __syncthreads();
  const int oc = t >> 3;
  const int orr = (t & 7) << 2;
  unsigned int p0, p1;
  cvt2(tile[orr][oc], tile[orr + 1][oc], &p0);
  cvt2(tile[orr + 2][oc], tile[orr + 3][oc], &p1);
  uint2 pk; pk.x = p0; pk.y = p1;
  *(uint2*)(out + mbase + (size_t)(c0 + oc) * R + r0 + orr) = pk;
}

// ---------------- biases -> f32, [NE+1] stacked (slot NE = shared) ----------
__global__ void cvtb_kernel(const void* b1, const void* b3, const void* b2,
                            const void* sb1, const void* sb3, const void* sb2,
                            const int* __restrict__ dflag,
                            float* __restrict__ bf1, float* __restrict__ bf3,
                            float* __restrict__ bf2o) {
  int i = blockIdx.x * blockDim.x + threadIdx.x;
  const int nh = (NE + 1) * HH, nd = (NE + 1) * DD;
  const bool f32 = dflag[0] != 0;
  auto get = [&](const void* pm, const void* ps, int idx, int per) -> float {
    int mat = idx / per, j = idx - mat * per;
    if (f32) return (mat < NE) ? ((const float*)pm)[(size_t)mat * per + j]
                               : ((const float*)ps)[j];
    return bf2f((mat < NE) ? ((const unsigned short*)pm)[(size_t)mat * per + j]
                           : ((const unsigned short*)ps)[j]);
  };
  if (i < nh) bf1[i] = get(b1, sb1, i, HH);
  else if (i < 2 * nh) bf3[i - nh] = get(b3, sb3, i - nh, HH);
  else if (i < 2 * nh + nd) bf2o[i - 2 * nh] = get(b2, sb2, i - 2 * nh, DD);
}

// ---------------- gate: one wave per token ----------------
template <class T>
__device__ void gate_body(const T* __restrict__ x,
                          const T* __restrict__ gw,
                          const T* __restrict__ gb,
                          int* __restrict__ tok_eidx,
                          float* __restrict__ tok_w, int T_) {
  int t = (int)((blockIdx.x * blockDim.x + threadIdx.x) >> 6);
  int lane = threadIdx.x & 63;
  if (t >= T_) return;
  const T* xr = x + (size_t)t * DD;
  float acc[NE];
#pragma unroll
  for (int e = 0; e < NE; e++) acc[e] = 0.f;
  for (int i = lane; i < DD; i += 64) {
    float xv = tof(xr[i]);
#pragma unroll
    for (int e = 0; e < NE; e++) acc[e] += xv * tof(gw[e * DD + i]);
  }
#pragma unroll
  for (int off = 32; off > 0; off >>= 1) {
#pragma unroll
    for (int e = 0; e < NE; e++) acc[e] += __shfl_xor(acc[e], off);
  }
  if (lane == 0) {
    float mx = acc[0];
#pragma unroll
    for (int e = 1; e < NE; e++) mx = fmaxf(mx, acc[e]);
    float s = 0.f, sc[NE], bi[NE];
#pragma unroll
    for (int e = 0; e < NE; e++) { sc[e] = expf(acc[e] - mx); s += sc[e]; }
    float inv = 1.f / s;
#pragma unroll
    for (int e = 0; e < NE; e++) { sc[e] *= inv; bi[e] = sc[e] + tof(gb[e]); }
    int i1 = 0;
#pragma unroll
    for (int e = 1; e < NE; e++) if (bi[e] > bi[i1]) i1 = e;
    int i2 = (i1 == 0) ? 1 : 0;
#pragma unroll
    for (int e = 0; e < NE; e++) if (e != i1 && bi[e] > bi[i2]) i2 = e;
    tok_eidx[t * 2] = i1; tok_eidx[t * 2 + 1] = i2;
    tok_w[t * 2] = sc[i1]; tok_w[t * 2 + 1] = sc[i2];
  }
}

__global__ void gate_kernel(const void* x, const void* gw, const void* gb,
                            const int* __restrict__ dflag,
                            int* tok_eidx, float* tok_w, int T_) {
  if (dflag[0])
    gate_body<float>((const float*)x, (const float*)gw, (const float*)gb,
                     tok_eidx, tok_w, T_);
  else
    gate_body<unsigned short>((const unsigned short*)x, (const unsigned short*)gw,
                              (const unsigned short*)gb, tok_eidx, tok_w, T_);
}

// ------- fused count + scan + scatter (single block); also records pos -------
__global__ void prep_kernel(const int* __restrict__ tok_eidx,
                            const float* __restrict__ tok_w,
                            int* __restrict__ meta,
                            int* __restrict__ rows_tok,
                            float* __restrict__ rows_wgt,
                            int* __restrict__ tok_pos,
                            int t0, int TS) {
  __shared__ int cnt[NE];
  __shared__ int off[NE];
  const int tid = threadIdx.x;
  if (tid < NE) cnt[tid] = 0;
  __syncthreads();
  const int n2 = TS * 2;
  const int* te = tok_eidx + (size_t)t0 * 2;
  const float* tw = tok_w + (size_t)t0 * 2;
  for (int i = tid; i < n2; i += (int)blockDim.x) atomicAdd(&cnt[te[i]], 1);
  __syncthreads();
  if (tid == 0) {
    int s = 0;
#pragma unroll
    for (int e = 0; e < NE; e++) { off[e] = s; meta[16 + e] = s; s += cnt[e]; }
    meta[16 + NE] = s;
  }
  __syncthreads();
  for (int i = tid; i < n2; i += (int)blockDim.x) {
    int pos = atomicAdd(&off[te[i]], 1);
    rows_tok[pos] = t0 + (i >> 1);
    rows_wgt[pos] = tw[i];
    tok_pos[(size_t)(t0 + (i >> 1)) * 2 + (i & 1)] = pos;
  }
}

// ---------------- combine: d_out[t] += r_out[pos0] + r_out[pos1] ----------
__global__ void combine_kernel(const float4* __restrict__ r_out,
                               const int* __restrict__ tok_pos,
                               float4* __restrict__ out, int t0, int TS) {
  const int C4 = DD / 4;
  int i = blockIdx.x * blockDim.x + threadIdx.x;
  int n4 = TS * C4;
  int st = gridDim.x * blockDim.x;
  for (; i < n4; i += st) {
    int tl = i / C4, c = i - tl * C4;
    int t = t0 + tl;
    int p0 = tok_pos[t * 2], p1 = tok_pos[t * 2 + 1];
    float4 a = out[(size_t)t * C4 + c];
    float4 b = r_out[(size_t)p0 * C4 + c];
    float4 d = r_out[(size_t)p1 * C4 + c];
    a.x += b.x + d.x; a.y += b.y + d.y;
    a.z += b.z + d.z; a.w += b.w + d.w;
    out[(size_t)t * C4 + c] = a;
  }
}

// ============ up-projection: M256 x N128, BK=32, 3-buffer LDS (96KB),
// ============ 2-ahead global_load_lds prefetch + counted vmcnt, ONE raw
// ============ barrier per K-step. XOR swizzle: slot ^= (row>>1)&3 (64B rows).
// XCD-affinity decode: all m-tiles of a panel share id%8 -> same XCD L2.
__global__ __launch_bounds__(512, 2)
void ffn_up_kernel(const unsigned short* __restrict__ xb,
                   const unsigned short* __restrict__ wt1,
                   const unsigned short* __restrict__ wt3,
                   const float* __restrict__ bf1, const float* __restrict__ bf3,
                   const int* __restrict__ meta,
                   const int* __restrict__ rows_tok,
                   unsigned short* __restrict__ h_buf,
                   unsigned short* __restrict__ sh_buf,
                   int t0, int TS, int my) {
  const int NX = HH / 128;          // 11 n-tiles
  const int P = NX * (NE + 1);      // 99 panels
  const int id = blockIdx.x;
  const int xcd = id & 7;
  const int rest = id >> 3;
  const int mtile = rest % my;
  const int chunk = rest / my;
  const int panel = chunk * 8 + xcd;
  if (panel >= P) return;
  const int z = panel / NX;
  const int n0 = (panel - z * NX) * 128;

  const bool shx = (z == NE);
  int g0, cnt;
  unsigned short* ho;
  if (shx) { g0 = 0; cnt = TS; ho = sh_buf; }
  else {
    g0 = meta[16 + z]; cnt = meta[17 + z] - g0;
    ho = h_buf + (size_t)g0 * HH;
  }
  if (mtile * 256 >= cnt) return;
  const unsigned short* wa = wt1 + (size_t)z * HH * DD;  // [HH][DD] bf16
  const unsigned short* wb = wt3 + (size_t)z * HH * DD;

  // per buffer (16384 shorts = 32KB): A 256x32 (8192) + B1 128x32 (4096)
  // + B3 128x32 (4096). 3 buffers = 96KB.
  __shared__ alignas(16) unsigned short lds[3 * 16384];

  const int tid = threadIdx.x;
  const int lane = tid & 63, wid = tid >> 6;

  // A granules: g = c*512 + tid; row = g>>2 (0..255), slot = g&3
  size_t aoff[2];
#pragma unroll
  for (int c = 0; c < 2; c++) {
    int g = c * 512 + tid;
    int r = g >> 2, s = g & 3;
    int m = mtile * 256 + r;
    int rr = (m < cnt) ? m : (cnt - 1);
    int srow = shx ? (t0 + rr) : rows_tok[g0 + rr];
    aoff[c] = (size_t)srow * DD + ((s ^ ((r >> 1) & 3)) << 3);
  }
  // B granule: row = tid>>2 (0..127), slot = tid&3
  size_t boffs;
  {
    int rb = tid >> 2, sb = tid & 3;
    boffs = (size_t)(n0 + rb) * DD + ((sb ^ ((rb >> 1) & 3)) << 3);
  }
  const int wbase = wid * 512;  // wave-uniform LDS elem base (HW adds lane*16B)

  const int ln15 = lane & 15;
  const int lg = lane >> 4;           // 0..3
  const int wr = (wid >> 1) << 6;     // 0,64,128,192
  const int wc = (wid & 1) << 6;      // 0,64

  f32x4 acc1[4][4], acc3[4][4];
#pragma unroll
  for (int a = 0; a < 4; a++)
#pragma unroll
    for (int b = 0; b < 4; b++) {
      acc1[a][b] = {0.f, 0.f, 0.f, 0.f};
      acc3[a][b] = {0.f, 0.f, 0.f, 0.f};
    }

  auto stage = [&](int buf, int k) {  // 4 gl16 per thread
    unsigned short* Lb = &lds[buf * 16384];
#pragma unroll
    for (int c = 0; c < 2; c++)
      gl16(xb + aoff[c] + k, Lb + c * 4096 + wbase);
    gl16(wa + boffs + k, Lb + 8192 + wbase);
    gl16(wb + boffs + k, Lb + 12288 + wbase);
  };

  const int NT = DD / 32;  // 32
  stage(0, 0);
  stage(1, 32);
  for (int t = 0; t < NT; ++t) {
    if (t + 1 < NT) asm volatile("s_waitcnt vmcnt(4)" ::: "memory");
    else            asm volatile("s_waitcnt vmcnt(0)" ::: "memory");
    asm volatile("s_barrier" ::: "memory");
    if (t + 2 < NT) stage((t + 2) % 3, (t + 2) * 32);
    const unsigned short* Lb = &lds[(t % 3) * 16384];
    bf16x8 af[4];
#pragma unroll
    for (int fm = 0; fm < 4; fm++) {
      int R = wr + fm * 16 + ln15;
      af[fm] = *(const bf16x8*)&Lb[R * 32 + ((lg ^ ((R >> 1) & 3)) << 3)];
    }
#pragma unroll
    for (int fn = 0; fn < 4; fn++) {
      int Rb = wc + fn * 16 + ln15;
      int o = Rb * 32 + ((lg ^ ((Rb >> 1) & 3)) << 3);
      bf16x8 b1v = *(const bf16x8*)&Lb[8192 + o];
      bf16x8 b3v = *(const bf16x8*)&Lb[12288 + o];
#pragma unroll
      for (int fm = 0; fm < 4; fm++) {
        acc1[fm][fn] = __builtin_amdgcn_mfma_f32_16x16x32_bf16(af[fm], b1v, acc1[fm][fn], 0, 0, 0);
        acc3[fm][fn] = __builtin_amdgcn_mfma_f32_16x16x32_bf16(af[fm], b3v, acc3[fm][fn], 0, 0, 0);
      }
    }
  }

  const int kq4 = lg << 2;
#pragma unroll
  for (int fm = 0; fm < 4; fm++) {
#pragma unroll
    for (int r = 0; r < 4; r++) {
      int m = mtile * 256 + wr + fm * 16 + kq4 + r;
      if (m < cnt) {
        unsigned short* orow = ho + (size_t)m * HH + n0;
#pragma unroll
        for (int fn = 0; fn < 4; fn++) {
          int nc = wc + fn * 16 + ln15;
          float g1 = acc1[fm][fn][r] + bf1[(size_t)z * HH + n0 + nc];
          float g3 = acc3[fm][fn][r] + bf3[(size_t)z * HH + n0 + nc];
          float u = g1 * g3;
          float hv = u * __builtin_amdgcn_rcpf(1.f + __expf(-u));  // silu(g1*g3)
          orow[nc] = f2bf(hv);
        }
      }
    }
  }
}

// ============ down-projection: M256 x N128, BK=32, 3-buffer (72KB),
// ============ same pipeline. Routed rows -> r_out; shared rows -> d_out.
__global__ __launch_bounds__(512, 2)
void ffn_down_kernel(const unsigned short* __restrict__ h_buf,
                     const unsigned short* __restrict__ sh_buf,
                     const unsigned short* __restrict__ wt2,
                     const float* __restrict__ bf2,
                     const int* __restrict__ meta,
                     const int* __restrict__ rows_tok,
                     const float* __restrict__ rows_wgt,
                     float* __restrict__ r_out,
                     float* __restrict__ out, int t0, int TS, int my) {
  const int NX = DD / 128;          // 8 n-tiles
  const int P = NX * (NE + 1);      // 72 panels
  const int id = blockIdx.x;
  const int xcd = id & 7;
  const int rest = id >> 3;
  const int mtile = rest % my;
  const int chunk = rest / my;
  const int panel = chunk * 8 + xcd;
  if (panel >= P) return;
  const int z = panel / NX;
  const int n0 = (panel - z * NX) * 128;

  const bool shx = (z == NE);
  int g0, cnt;
  const unsigned short* hb;
  if (shx) { g0 = 0; cnt = TS; hb = sh_buf; }
  else {
    g0 = meta[16 + z]; cnt = meta[17 + z] - g0;
    hb = h_buf + (size_t)g0 * HH;
  }
  if (mtile * 256 >= cnt) return;
  const unsigned short* ws = wt2 + (size_t)z * DD * HH;  // [DD][HH] bf16

  // per buffer (12288 shorts = 24KB): A 256x32 (8192) + B 128x32 (4096)
  __shared__ alignas(16) unsigned short lds[3 * 12288];

  const int tid = threadIdx.x;
  const int lane = tid & 63, wid = tid >> 6;

  size_t aoff[2];
#pragma unroll
  for (int c = 0; c < 2; c++) {
    int g = c * 512 + tid;
    int r = g >> 2, s = g & 3;
    int m = mtile * 256 + r;
    int rr = (m < cnt) ? m : (cnt - 1);
    aoff[c] = (size_t)rr * HH + ((s ^ ((r >> 1) & 3)) << 3);
  }
  size_t boffs;
  {
    int rb = tid >> 2, sb = tid & 3;
    boffs = (size_t)(n0 + rb) * HH + ((sb ^ ((rb >> 1) & 3)) << 3);
  }
  const int wbase = wid * 512;

  const int ln15 = lane & 15;
  const int lg = lane >> 4;
  const int wr = (wid >> 1) << 6;
  const int wc = (wid & 1) << 6;

  f32x4 acc[4][4];
#pragma unroll
  for (int a = 0; a < 4; a++)
#pragma unroll
    for (int b = 0; b < 4; b++) acc[a][b] = {0.f, 0.f, 0.f, 0.f};

  auto stage = [&](int buf, int k) {  // 3 gl16 per thread
    unsigned short* Lb = &lds[buf * 12288];
#pragma unroll
    for (int c = 0; c < 2; c++)
      gl16(hb + aoff[c] + k, Lb + c * 4096 + wbase);
    gl16(ws + boffs + k, Lb + 8192 + wbase);
  };

  const int NT = HH / 32;  // 44
  stage(0, 0);
  stage(1, 32);
  for (int t = 0; t < NT; ++t) {
    if (t + 1 < NT) asm volatile("s_waitcnt vmcnt(3)" ::: "memory");
    else            asm volatile("s_waitcnt vmcnt(0)" ::: "memory");
    asm volatile("s_barrier" ::: "memory");
    if (t + 2 < NT) stage((t + 2) % 3, (t + 2) * 32);
    const unsigned short* Lb = &lds[(t % 3) * 12288];
    bf16x8 af[4];
#pragma unroll
    for (int fm = 0; fm < 4; fm++) {
      int R = wr + fm * 16 + ln15;
      af[fm] = *(const bf16x8*)&Lb[R * 32 + ((lg ^ ((R >> 1) & 3)) << 3)];
    }
#pragma unroll
    for (int fn = 0; fn < 4; fn++) {
      int Rb = wc + fn * 16 + ln15;
      int o = Rb * 32 + ((lg ^ ((Rb >> 1) & 3)) << 3);
      bf16x8 bv = *(const bf16x8*)&Lb[8192 + o];
#pragma unroll
      for (int fm = 0; fm < 4; fm++)
        acc[fm][fn] = __builtin_amdgcn_mfma_f32_16x16x32_bf16(af[fm], bv, acc[fm][fn], 0, 0, 0);
    }
  }

  const int kq4 = lg << 2;
#pragma unroll
  for (int fm = 0; fm < 4; fm++) {
#pragma unroll
    for (int r4 = 0; r4 < 4; r4++) {
      int m = mtile * 256 + wr + fm * 16 + kq4 + r4;
      if (m < cnt) {
        float* orow;
        float wgt;
        if (shx) { orow = out + (size_t)(t0 + m) * DD + n0; wgt = 1.f; }
        else { orow = r_out + (size_t)(g0 + m) * DD + n0; wgt = rows_wgt[g0 + m]; }
#pragma unroll
        for (int fn = 0; fn < 4; fn++) {
          int nc = wc + fn * 16 + ln15;
          orow[nc] = wgt * (acc[fm][fn][r4] + bf2[(size_t)z * DD + n0 + nc]);
        }
      }
    }
  }
}

extern "C" void kernel_launch(void* const* d_in, const int* in_sizes, int n_in,
                              void* d_out, int out_size, void* d_ws, size_t ws_size,
                              hipStream_t stream) {
  const void* x   = d_in[0];
  const void* gw  = d_in[1];
  const void* gb  = d_in[2];
  const void* w1  = d_in[3];
  const void* b1  = d_in[4];
  const void* w3  = d_in[5];
  const void* b3  = d_in[6];
  const void* w2  = d_in[7];
  const void* b2  = d_in[8];
  const void* sw1 = d_in[9];
  const void* sb1 = d_in[10];
  const void* sw3 = d_in[11];
  const void* sb3 = d_in[12];
  const void* sw2 = d_in[13];
  const void* sb2 = d_in[14];

  const int T = in_sizes[0] / DD;  // 4096
  (void)n_in; (void)out_size;

  const size_t WMAT = (size_t)(NE + 1) * HH * DD;

  auto need = [&](int S) -> size_t {
    int TS = T / S;
    size_t o = 0;
    auto pad = [&](size_t b) { o = (o + b + 255) & ~(size_t)255; };
    pad(256);
    pad(32 * sizeof(int));
    pad((size_t)T * 2 * sizeof(int));        // tok_eidx
    pad((size_t)T * 2 * sizeof(float));      // tok_w
    pad((size_t)T * 2 * sizeof(int));        // tok_pos
    pad((size_t)T * DD * 2);                 // xb
    pad(WMAT * 2);
    pad(WMAT * 2);
    pad(WMAT * 2);
    pad((size_t)(NE + 1) * HH * sizeof(float));
    pad((size_t)(NE + 1) * HH * sizeof(float));
    pad((size_t)(NE + 1) * DD * sizeof(float));
    pad((size_t)TS * 2 * sizeof(int));       // rows_tok
    pad((size_t)TS * 2 * sizeof(float));     // rows_wgt
    pad((size_t)TS * 2 * HH * 2);            // h_buf
    pad((size_t)TS * HH * 2);                // sh_buf
    pad((size_t)TS * 2 * DD * sizeof(float)); // r_out
    return o;
  };
  int S = 32;
  {
    const int cand[6] = {1, 2, 4, 8, 16, 32};
    for (int ci = 0; ci < 6; ci++) {
      if (need(cand[ci]) <= ws_size) { S = cand[ci]; break; }
    }
  }
  const int TS = T / S;
  const int my = (TS + 255) / 256;

  char* w = (char*)d_ws;
  size_t off = 0;
  auto take = [&](size_t bytes) {
    char* p = w + off;
    off = (off + bytes + 255) & ~(size_t)255;
    return p;
  };
  int*   dflag    = (int*)  take(256);
  int*   meta     = (int*)  take(32 * sizeof(int));
  int*   tok_eidx = (int*)  take((size_t)T * 2 * sizeof(int));
  float* tok_w    = (float*)take((size_t)T * 2 * sizeof(float));
  int*   tok_pos  = (int*)  take((size_t)T * 2 * sizeof(int));
  unsigned short* xb  = (unsigned short*)take((size_t)T * DD * 2);
  unsigned short* wt1 = (unsigned short*)take(WMAT * 2);
  unsigned short* wt3 = (unsigned short*)take(WMAT * 2);
  unsigned short* wt2 = (unsigned short*)take(WMAT * 2);
  float* bf1 = (float*)take((size_t)(NE + 1) * HH * sizeof(float));
  float* bf3 = (float*)take((size_t)(NE + 1) * HH * sizeof(float));
  float* bf2 = (float*)take((size_t)(NE + 1) * DD * sizeof(float));
  int*   rows_tok = (int*)  take((size_t)TS * 2 * sizeof(int));
  float* rows_wgt = (float*)take((size_t)TS * 2 * sizeof(float));
  unsigned short* h_buf  = (unsigned short*)take((size_t)TS * 2 * HH * 2);
  unsigned short* sh_buf = (unsigned short*)take((size_t)TS * HH * 2);
  float* r_out = (float*)take((size_t)TS * 2 * DD * sizeof(float));

  sniff_kernel<<<1, 256, 0, stream>>>((const unsigned short*)x, dflag);

  cvtx_kernel<<<2048, 256, 0, stream>>>(x, dflag, xb, T * DD / 8);
  trans_kernel<<<dim3(HH / 32, DD / 32, NE + 1), 256, 0, stream>>>(w1, sw1, dflag, wt1, DD, HH);
  trans_kernel<<<dim3(HH / 32, DD / 32, NE + 1), 256, 0, stream>>>(w3, sw3, dflag, wt3, DD, HH);
  trans_kernel<<<dim3(DD / 32, HH / 32, NE + 1), 256, 0, stream>>>(w2, sw2, dflag, wt2, HH, DD);
  {
    int nb = (2 * (NE + 1) * HH + (NE + 1) * DD + 255) / 256;
    cvtb_kernel<<<nb, 256, 0, stream>>>(b1, b3, b2, sb1, sb3, sb2, dflag, bf1, bf3, bf2);
  }

  gate_kernel<<<(T + 3) / 4, 256, 0, stream>>>(x, gw, gb, dflag, tok_eidx, tok_w, T);

  // XCD-affinity 1-D grids
  const int upP = (HH / 128) * (NE + 1);    // 99
  const int dnP = (DD / 128) * (NE + 1);    // 72
  const int upGrid = 8 * ((upP + 7) / 8) * my;
  const int dnGrid = 8 * ((dnP + 7) / 8) * my;

  for (int s = 0; s < S; s++) {
    const int t0 = s * TS;
    prep_kernel<<<1, 1024, 0, stream>>>(tok_eidx, tok_w, meta, rows_tok, rows_wgt,
                                        tok_pos, t0, TS);
    ffn_up_kernel<<<upGrid, 512, 0, stream>>>(
        xb, wt1, wt3, bf1, bf3, meta, rows_tok, h_buf, sh_buf, t0, TS, my);
    ffn_down_kernel<<<dnGrid, 512, 0, stream>>>(
        h_buf, sh_buf, wt2, bf2, meta, rows_tok, rows_wgt, r_out,
        (float*)d_out, t0, TS, my);
    combine_kernel<<<1024, 256, 0, stream>>>((const float4*)r_out, tok_pos,
                                             (float4*)d_out, t0, TS);
  }
}

// Round 7
// 425.609 us; speedup vs baseline: 1.0708x; 1.0340x over previous
//
#include <hip/hip_runtime.h>
#include <math.h>

#define DD 1024   // hidden dim
#define HH 1408   // moe inter dim
#define NE 8      // experts

typedef __attribute__((ext_vector_type(8))) __bf16 bf16x8;
typedef __attribute__((ext_vector_type(4))) float f32x4;

__device__ __forceinline__ float bf2f(unsigned short u) {
  union { unsigned int i; float f; } v; v.i = ((unsigned int)u) << 16; return v.f;
}
__device__ __forceinline__ unsigned short f2bf(float f) {
  union { float f; unsigned int i; } v; v.f = f;
  unsigned int r = v.i + 0x7FFFu + ((v.i >> 16) & 1u);  // RNE
  return (unsigned short)(r >> 16);
}
__device__ __forceinline__ float tof(float f) { return f; }
__device__ __forceinline__ float tof(unsigned short u) { return bf2f(u); }

// pack bf16(a) | bf16(b)<<16 in ONE instruction (RNE, gfx950)
__device__ __forceinline__ void cvt2(float a, float b, unsigned int* o) {
  asm("v_cvt_pk_bf16_f32 %0, %1, %2" : "=v"(*o) : "v"(a), "v"(b));
}

__device__ __forceinline__ void ld8cvt(const float* p, unsigned int* o) {
  float4 a = *(const float4*)p;
  float4 b = *(const float4*)(p + 4);
  cvt2(a.x, a.y, o + 0); cvt2(a.z, a.w, o + 1);
  cvt2(b.x, b.y, o + 2); cvt2(b.z, b.w, o + 3);
}

// async global->LDS, 16 bytes per lane; LDS ptr must be wave-uniform base
// (HW adds lane*16 itself)
typedef unsigned int __attribute__((address_space(1))) gu32;
typedef unsigned int __attribute__((address_space(3))) lu32;
__device__ __forceinline__ void gl16(const unsigned short* g, unsigned short* l) {
  __builtin_amdgcn_global_load_lds((const gu32*)g, (lu32*)l, 16, 0, 0);
}

// ---------------- sniff input dtype: 1 = fp32, 0 = bf16 ----------------
__global__ void sniff_kernel(const unsigned short* __restrict__ xw,
                             int* __restrict__ dflag) {
  __shared__ int cnt;
  if (threadIdx.x == 0) cnt = 0;
  __syncthreads();
  unsigned short v = xw[threadIdx.x];
  int e = (v >> 7) & 0xFF;
  if (e >= 100 && e <= 140) atomicAdd(&cnt, 1);
  __syncthreads();
  if (threadIdx.x == 0) dflag[0] = (cnt < 230) ? 1 : 0;
}

// ---------------- convert x -> bf16 ----------------
__global__ void cvtx_kernel(const void* __restrict__ x,
                            const int* __restrict__ dflag,
                            unsigned short* __restrict__ xb, int n8) {
  int i = blockIdx.x * blockDim.x + threadIdx.x;
  int st = gridDim.x * blockDim.x;
  if (dflag[0]) {
    const float* xs = (const float*)x;
    for (; i < n8; i += st) {
      unsigned int o[4];
      ld8cvt(xs + (size_t)i * 8, o);
      *(uint4*)(xb + (size_t)i * 8) = *(uint4*)o;
    }
  } else {
    const uint4* xs = (const uint4*)x;
    for (; i < n8; i += st) *(uint4*)(xb + (size_t)i * 8) = xs[i];
  }
}

// ---------------- transpose+convert weights: [mat][R][C] -> [mat][C][R] bf16 ----
__global__ void trans_kernel(const void* __restrict__ wmain,
                             const void* __restrict__ wsh,
                             const int* __restrict__ dflag,
                             unsigned short* __restrict__ out, int R, int C) {
  __shared__ float tile[32][33];
  const int mat = blockIdx.z;
  const int r0 = blockIdx.y << 5, c0 = blockIdx.x << 5;
  const int t = threadIdx.x;                 // 256 threads
  const int lr = t >> 3, lc = (t & 7) << 2;
  const size_t mbase = (size_t)mat * R * C;
  if (dflag[0]) {
    const float* src = (mat < NE) ? ((const float*)wmain + mbase) : (const float*)wsh;
    float4 v = *(const float4*)(src + (size_t)(r0 + lr) * C + c0 + lc);
    tile[lr][lc] = v.x; tile[lr][lc + 1] = v.y;
    tile[lr][lc + 2] = v.z; tile[lr][lc + 3] = v.w;
  } else {
    const unsigned short* src = (mat < NE) ? ((const unsigned short*)wmain + mbase)
                                           : (const unsigned short*)wsh;
    ushort4 v = *(const ushort4*)(src + (size_t)(r0 + lr) * C + c0 + lc);
    tile[lr][lc] = bf2f(v.x); tile[lr][lc + 1] = bf2f(v.y);
    tile[lr][lc + 2] = bf2f(v.z); tile[lr][lc + 3] = bf2f(v.w);
  }
  __syncthreads();
  const int oc = t >> 3;
  const int orr = (t & 7) << 2;
  unsigned int p0, p1;
  cvt2(tile[orr][oc], tile[orr + 1][oc], &p0);
  cvt2(tile[orr + 2][oc], tile[orr + 3][oc], &p1);
  uint2 pk; pk.x = p0; pk.y = p1;
  *(uint2*)(out + mbase + (size_t)(c0 + oc) * R + r0 + orr) = pk;
}

// ---------------- biases -> f32, [NE+1] stacked (slot NE = shared) ----------
__global__ void cvtb_kernel(const void* b1, const void* b3, const void* b2,
                            const void* sb1, const void* sb3, const void* sb2,
                            const int* __restrict__ dflag,
                            float* __restrict__ bf1, float* __restrict__ bf3,
                            float* __restrict__ bf2o) {
  int i = blockIdx.x * blockDim.x + threadIdx.x;
  const int nh = (NE + 1) * HH, nd = (NE + 1) * DD;
  const bool f32 = dflag[0] != 0;
  auto get = [&](const void* pm, const void* ps, int idx, int per) -> float {
    int mat = idx / per, j = idx - mat * per;
    if (f32) return (mat < NE) ? ((const float*)pm)[(size_t)mat * per + j]
                               : ((const float*)ps)[j];
    return bf2f((mat < NE) ? ((const unsigned short*)pm)[(size_t)mat * per + j]
                           : ((const unsigned short*)ps)[j]);
  };
  if (i < nh) bf1[i] = get(b1, sb1, i, HH);
  else if (i < 2 * nh) bf3[i - nh] = get(b3, sb3, i - nh, HH);
  else if (i < 2 * nh + nd) bf2o[i - 2 * nh] = get(b2, sb2, i - 2 * nh, DD);
}

// ---------------- gate: one wave per token ----------------
template <class T>
__device__ void gate_body(const T* __restrict__ x,
                          const T* __restrict__ gw,
                          const T* __restrict__ gb,
                          int* __restrict__ tok_eidx,
                          float* __restrict__ tok_w, int T_) {
  int t = (int)((blockIdx.x * blockDim.x + threadIdx.x) >> 6);
  int lane = threadIdx.x & 63;
  if (t >= T_) return;
  const T* xr = x + (size_t)t * DD;
  float acc[NE];
#pragma unroll
  for (int e = 0; e < NE; e++) acc[e] = 0.f;
  for (int i = lane; i < DD; i += 64) {
    float xv = tof(xr[i]);
#pragma unroll
    for (int e = 0; e < NE; e++) acc[e] += xv * tof(gw[e * DD + i]);
  }
#pragma unroll
  for (int off = 32; off > 0; off >>= 1) {
#pragma unroll
    for (int e = 0; e < NE; e++) acc[e] += __shfl_xor(acc[e], off);
  }
  if (lane == 0) {
    float mx = acc[0];
#pragma unroll
    for (int e = 1; e < NE; e++) mx = fmaxf(mx, acc[e]);
    float s = 0.f, sc[NE], bi[NE];
#pragma unroll
    for (int e = 0; e < NE; e++) { sc[e] = expf(acc[e] - mx); s += sc[e]; }
    float inv = 1.f / s;
#pragma unroll
    for (int e = 0; e < NE; e++) { sc[e] *= inv; bi[e] = sc[e] + tof(gb[e]); }
    int i1 = 0;
#pragma unroll
    for (int e = 1; e < NE; e++) if (bi[e] > bi[i1]) i1 = e;
    int i2 = (i1 == 0) ? 1 : 0;
#pragma unroll
    for (int e = 0; e < NE; e++) if (e != i1 && bi[e] > bi[i2]) i2 = e;
    tok_eidx[t * 2] = i1; tok_eidx[t * 2 + 1] = i2;
    tok_w[t * 2] = sc[i1]; tok_w[t * 2 + 1] = sc[i2];
  }
}

__global__ void gate_kernel(const void* x, const void* gw, const void* gb,
                            const int* __restrict__ dflag,
                            int* tok_eidx, float* tok_w, int T_) {
  if (dflag[0])
    gate_body<float>((const float*)x, (const float*)gw, (const float*)gb,
                     tok_eidx, tok_w, T_);
  else
    gate_body<unsigned short>((const unsigned short*)x, (const unsigned short*)gw,
                              (const unsigned short*)gb, tok_eidx, tok_w, T_);
}

// ------- fused count + scan + scatter (single block); also records pos -------
__global__ void prep_kernel(const int* __restrict__ tok_eidx,
                            const float* __restrict__ tok_w,
                            int* __restrict__ meta,
                            int* __restrict__ rows_tok,
                            float* __restrict__ rows_wgt,
                            int* __restrict__ tok_pos,
                            int t0, int TS) {
  __shared__ int cnt[NE];
  __shared__ int off[NE];
  const int tid = threadIdx.x;
  if (tid < NE) cnt[tid] = 0;
  __syncthreads();
  const int n2 = TS * 2;
  const int* te = tok_eidx + (size_t)t0 * 2;
  const float* tw = tok_w + (size_t)t0 * 2;
  for (int i = tid; i < n2; i += (int)blockDim.x) atomicAdd(&cnt[te[i]], 1);
  __syncthreads();
  if (tid == 0) {
    int s = 0;
#pragma unroll
    for (int e = 0; e < NE; e++) { off[e] = s; meta[16 + e] = s; s += cnt[e]; }
    meta[16 + NE] = s;
  }
  __syncthreads();
  for (int i = tid; i < n2; i += (int)blockDim.x) {
    int pos = atomicAdd(&off[te[i]], 1);
    rows_tok[pos] = t0 + (i >> 1);
    rows_wgt[pos] = tw[i];
    tok_pos[(size_t)(t0 + (i >> 1)) * 2 + (i & 1)] = pos;
  }
}

// ---------------- combine: d_out[t] += r_out[pos0] + r_out[pos1] ----------
__global__ void combine_kernel(const float4* __restrict__ r_out,
                               const int* __restrict__ tok_pos,
                               float4* __restrict__ out, int t0, int TS) {
  const int C4 = DD / 4;
  int i = blockIdx.x * blockDim.x + threadIdx.x;
  int n4 = TS * C4;
  int st = gridDim.x * blockDim.x;
  for (; i < n4; i += st) {
    int tl = i / C4, c = i - tl * C4;
    int t = t0 + tl;
    int p0 = tok_pos[t * 2], p1 = tok_pos[t * 2 + 1];
    float4 a = out[(size_t)t * C4 + c];
    float4 b = r_out[(size_t)p0 * C4 + c];
    float4 d = r_out[(size_t)p1 * C4 + c];
    a.x += b.x + d.x; a.y += b.y + d.y;
    a.z += b.z + d.z; a.w += b.w + d.w;
    out[(size_t)t * C4 + c] = a;
  }
}

// ============ up-projection: M128 x N128, BK=32, 2-buf (48KB LDS),
// ============ gl16 staging, XOR swizzle slot^((row>>1)&3), 8 waves of 32x64,
// ============ ~116 regs -> 2 blocks/CU (16 waves). vmcnt(0)+syncthreads loop.
// XCD-affinity decode: all m-tiles of a panel share id%8 -> same XCD L2.
__global__ __launch_bounds__(512, 4)
void ffn_up_kernel(const unsigned short* __restrict__ xb,
                   const unsigned short* __restrict__ wt1,
                   const unsigned short* __restrict__ wt3,
                   const float* __restrict__ bf1, const float* __restrict__ bf3,
                   const int* __restrict__ meta,
                   const int* __restrict__ rows_tok,
                   unsigned short* __restrict__ h_buf,
                   unsigned short* __restrict__ sh_buf,
                   int t0, int TS, int my) {
  const int NX = HH / 128;          // 11 n-tiles
  const int P = NX * (NE + 1);      // 99 panels
  const int id = blockIdx.x;
  const int xcd = id & 7;
  const int rest = id >> 3;
  const int mtile = rest % my;
  const int chunk = rest / my;
  const int panel = chunk * 8 + xcd;
  if (panel >= P) return;
  const int z = panel / NX;
  const int n0 = (panel - z * NX) * 128;

  const bool shx = (z == NE);
  int g0, cnt;
  unsigned short* ho;
  if (shx) { g0 = 0; cnt = TS; ho = sh_buf; }
  else {
    g0 = meta[16 + z]; cnt = meta[17 + z] - g0;
    ho = h_buf + (size_t)g0 * HH;
  }
  if (mtile * 128 >= cnt) return;
  const unsigned short* wa = wt1 + (size_t)z * HH * DD;  // [HH][DD] bf16
  const unsigned short* wb = wt3 + (size_t)z * HH * DD;

  // per buffer (12288 shorts = 24KB): A 128x32 + B1 128x32 + B3 128x32
  __shared__ alignas(16) unsigned short lds[2 * 12288];

  const int tid = threadIdx.x;
  const int lane = tid & 63, wid = tid >> 6;

  // one 16B granule per thread per array: row = tid>>2, slot = tid&3
  const int grow = tid >> 2, gslot = tid & 3;
  const int gcol = (gslot ^ ((grow >> 1) & 3)) << 3;  // swizzled source col
  size_t aoffs;
  {
    int m = mtile * 128 + grow;
    int rr = (m < cnt) ? m : (cnt - 1);
    int srow = shx ? (t0 + rr) : rows_tok[g0 + rr];
    aoffs = (size_t)srow * DD + gcol;
  }
  const size_t boffs = (size_t)(n0 + grow) * DD + gcol;
  const int wbase = wid * 512;  // wave-uniform LDS elem base (HW adds lane*16B)

  const int ln15 = lane & 15;
  const int lg = lane >> 4;           // 0..3
  const int wr = (wid >> 1) << 5;     // 0,32,64,96  (M)
  const int wc = (wid & 1) << 6;      // 0,64        (N)

  f32x4 acc1[2][4], acc3[2][4];
#pragma unroll
  for (int a = 0; a < 2; a++)
#pragma unroll
    for (int b = 0; b < 4; b++) {
      acc1[a][b] = {0.f, 0.f, 0.f, 0.f};
      acc3[a][b] = {0.f, 0.f, 0.f, 0.f};
    }

  auto stage = [&](int buf, int k) {  // 3 gl16 per thread
    unsigned short* Lb = &lds[buf * 12288];
    gl16(xb + aoffs + k, Lb + wbase);
    gl16(wa + boffs + k, Lb + 4096 + wbase);
    gl16(wb + boffs + k, Lb + 8192 + wbase);
  };

  const int NT = DD / 32;  // 32
  stage(0, 0);
  for (int t = 0; t < NT; ++t) {
    asm volatile("s_waitcnt vmcnt(0)" ::: "memory");
    __syncthreads();
    if (t + 1 < NT) stage((t + 1) & 1, (t + 1) * 32);
    const unsigned short* Lb = &lds[(t & 1) * 12288];
    bf16x8 af[2];
#pragma unroll
    for (int fm = 0; fm < 2; fm++) {
      int R = wr + fm * 16 + ln15;
      af[fm] = *(const bf16x8*)&Lb[R * 32 + ((lg ^ ((R >> 1) & 3)) << 3)];
    }
#pragma unroll
    for (int fn = 0; fn < 4; fn++) {
      int Rb = wc + fn * 16 + ln15;
      int o = Rb * 32 + ((lg ^ ((Rb >> 1) & 3)) << 3);
      bf16x8 b1v = *(const bf16x8*)&Lb[4096 + o];
      bf16x8 b3v = *(const bf16x8*)&Lb[8192 + o];
#pragma unroll
      for (int fm = 0; fm < 2; fm++) {
        acc1[fm][fn] = __builtin_amdgcn_mfma_f32_16x16x32_bf16(af[fm], b1v, acc1[fm][fn], 0, 0, 0);
        acc3[fm][fn] = __builtin_amdgcn_mfma_f32_16x16x32_bf16(af[fm], b3v, acc3[fm][fn], 0, 0, 0);
      }
    }
  }

  const int kq4 = lg << 2;
#pragma unroll
  for (int fm = 0; fm < 2; fm++) {
#pragma unroll
    for (int r = 0; r < 4; r++) {
      int m = mtile * 128 + wr + fm * 16 + kq4 + r;
      if (m < cnt) {
        unsigned short* orow = ho + (size_t)m * HH + n0;
#pragma unroll
        for (int fn = 0; fn < 4; fn++) {
          int nc = wc + fn * 16 + ln15;
          float g1 = acc1[fm][fn][r] + bf1[(size_t)z * HH + n0 + nc];
          float g3 = acc3[fm][fn][r] + bf3[(size_t)z * HH + n0 + nc];
          float u = g1 * g3;
          float hv = u * __builtin_amdgcn_rcpf(1.f + __expf(-u));  // silu(g1*g3)
          orow[nc] = f2bf(hv);
        }
      }
    }
  }
}

// ============ down-projection: M128 x N128, BK=32, 2-buf (32KB LDS),
// ============ same structure. Routed rows -> r_out; shared rows -> d_out.
__global__ __launch_bounds__(512, 4)
void ffn_down_kernel(const unsigned short* __restrict__ h_buf,
                     const unsigned short* __restrict__ sh_buf,
                     const unsigned short* __restrict__ wt2,
                     const float* __restrict__ bf2,
                     const int* __restrict__ meta,
                     const int* __restrict__ rows_tok,
                     const float* __restrict__ rows_wgt,
                     float* __restrict__ r_out,
                     float* __restrict__ out, int t0, int TS, int my) {
  const int NX = DD / 128;          // 8 n-tiles
  const int P = NX * (NE + 1);      // 72 panels
  const int id = blockIdx.x;
  const int xcd = id & 7;
  const int rest = id >> 3;
  const int mtile = rest % my;
  const int chunk = rest / my;
  const int panel = chunk * 8 + xcd;
  if (panel >= P) return;
  const int z = panel / NX;
  const int n0 = (panel - z * NX) * 128;

  const bool shx = (z == NE);
  int g0, cnt;
  const unsigned short* hb;
  if (shx) { g0 = 0; cnt = TS; hb = sh_buf; }
  else {
    g0 = meta[16 + z]; cnt = meta[17 + z] - g0;
    hb = h_buf + (size_t)g0 * HH;
  }
  if (mtile * 128 >= cnt) return;
  const unsigned short* ws = wt2 + (size_t)z * DD * HH;  // [DD][HH] bf16

  // per buffer (8192 shorts = 16KB): A 128x32 + B 128x32
  __shared__ alignas(16) unsigned short lds[2 * 8192];

  const int tid = threadIdx.x;
  const int lane = tid & 63, wid = tid >> 6;

  const int grow = tid >> 2, gslot = tid & 3;
  const int gcol = (gslot ^ ((grow >> 1) & 3)) << 3;
  size_t aoffs;
  {
    int m = mtile * 128 + grow;
    int rr = (m < cnt) ? m : (cnt - 1);
    aoffs = (size_t)rr * HH + gcol;
  }
  const size_t boffs = (size_t)(n0 + grow) * HH + gcol;
  const int wbase = wid * 512;

  const int ln15 = lane & 15;
  const int lg = lane >> 4;
  const int wr = (wid >> 1) << 5;
  const int wc = (wid & 1) << 6;

  f32x4 acc[2][4];
#pragma unroll
  for (int a = 0; a < 2; a++)
#pragma unroll
    for (int b = 0; b < 4; b++) acc[a][b] = {0.f, 0.f, 0.f, 0.f};

  auto stage = [&](int buf, int k) {  // 2 gl16 per thread
    unsigned short* Lb = &lds[buf * 8192];
    gl16(hb + aoffs + k, Lb + wbase);
    gl16(ws + boffs + k, Lb + 4096 + wbase);
  };

  const int NT = HH / 32;  // 44
  stage(0, 0);
  for (int t = 0; t < NT; ++t) {
    asm volatile("s_waitcnt vmcnt(0)" ::: "memory");
    __syncthreads();
    if (t + 1 < NT) stage((t + 1) & 1, (t + 1) * 32);
    const unsigned short* Lb = &lds[(t & 1) * 8192];
    bf16x8 af[2];
#pragma unroll
    for (int fm = 0; fm < 2; fm++) {
      int R = wr + fm * 16 + ln15;
      af[fm] = *(const bf16x8*)&Lb[R * 32 + ((lg ^ ((R >> 1) & 3)) << 3)];
    }
#pragma unroll
    for (int fn = 0; fn < 4; fn++) {
      int Rb = wc + fn * 16 + ln15;
      int o = Rb * 32 + ((lg ^ ((Rb >> 1) & 3)) << 3);
      bf16x8 bv = *(const bf16x8*)&Lb[4096 + o];
#pragma unroll
      for (int fm = 0; fm < 2; fm++)
        acc[fm][fn] = __builtin_amdgcn_mfma_f32_16x16x32_bf16(af[fm], bv, acc[fm][fn], 0, 0, 0);
    }
  }

  const int kq4 = lg << 2;
#pragma unroll
  for (int fm = 0; fm < 2; fm++) {
#pragma unroll
    for (int r4 = 0; r4 < 4; r4++) {
      int m = mtile * 128 + wr + fm * 16 + kq4 + r4;
      if (m < cnt) {
        float* orow;
        float wgt;
        if (shx) { orow = out + (size_t)(t0 + m) * DD + n0; wgt = 1.f; }
        else { orow = r_out + (size_t)(g0 + m) * DD + n0; wgt = rows_wgt[g0 + m]; }
#pragma unroll
        for (int fn = 0; fn < 4; fn++) {
          int nc = wc + fn * 16 + ln15;
          orow[nc] = wgt * (acc[fm][fn][r4] + bf2[(size_t)z * DD + n0 + nc]);
        }
      }
    }
  }
}

extern "C" void kernel_launch(void* const* d_in, const int* in_sizes, int n_in,
                              void* d_out, int out_size, void* d_ws, size_t ws_size,
                              hipStream_t stream) {
  const void* x   = d_in[0];
  const void* gw  = d_in[1];
  const void* gb  = d_in[2];
  const void* w1  = d_in[3];
  const void* b1  = d_in[4];
  const void* w3  = d_in[5];
  const void* b3  = d_in[6];
  const void* w2  = d_in[7];
  const void* b2  = d_in[8];
  const void* sw1 = d_in[9];
  const void* sb1 = d_in[10];
  const void* sw3 = d_in[11];
  const void* sb3 = d_in[12];
  const void* sw2 = d_in[13];
  const void* sb2 = d_in[14];

  const int T = in_sizes[0] / DD;  // 4096
  (void)n_in; (void)out_size;

  const size_t WMAT = (size_t)(NE + 1) * HH * DD;

  auto need = [&](int S) -> size_t {
    int TS = T / S;
    size_t o = 0;
    auto pad = [&](size_t b) { o = (o + b + 255) & ~(size_t)255; };
    pad(256);
    pad(32 * sizeof(int));
    pad((size_t)T * 2 * sizeof(int));        // tok_eidx
    pad((size_t)T * 2 * sizeof(float));      // tok_w
    pad((size_t)T * 2 * sizeof(int));        // tok_pos
    pad((size_t)T * DD * 2);                 // xb
    pad(WMAT * 2);
    pad(WMAT * 2);
    pad(WMAT * 2);
    pad((size_t)(NE + 1) * HH * sizeof(float));
    pad((size_t)(NE + 1) * HH * sizeof(float));
    pad((size_t)(NE + 1) * DD * sizeof(float));
    pad((size_t)TS * 2 * sizeof(int));       // rows_tok
    pad((size_t)TS * 2 * sizeof(float));     // rows_wgt
    pad((size_t)TS * 2 * HH * 2);            // h_buf
    pad((size_t)TS * HH * 2);                // sh_buf
    pad((size_t)TS * 2 * DD * sizeof(float)); // r_out
    return o;
  };
  int S = 32;
  {
    const int cand[6] = {1, 2, 4, 8, 16, 32};
    for (int ci = 0; ci < 6; ci++) {
      if (need(cand[ci]) <= ws_size) { S = cand[ci]; break; }
    }
  }
  const int TS = T / S;
  const int my = (TS + 127) / 128;

  char* w = (char*)d_ws;
  size_t off = 0;
  auto take = [&](size_t bytes) {
    char* p = w + off;
    off = (off + bytes + 255) & ~(size_t)255;
    return p;
  };
  int*   dflag    = (int*)  take(256);
  int*   meta     = (int*)  take(32 * sizeof(int));
  int*   tok_eidx = (int*)  take((size_t)T * 2 * sizeof(int));
  float* tok_w    = (float*)take((size_t)T * 2 * sizeof(float));
  int*   tok_pos  = (int*)  take((size_t)T * 2 * sizeof(int));
  unsigned short* xb  = (unsigned short*)take((size_t)T * DD * 2);
  unsigned short* wt1 = (unsigned short*)take(WMAT * 2);
  unsigned short* wt3 = (unsigned short*)take(WMAT * 2);
  unsigned short* wt2 = (unsigned short*)take(WMAT * 2);
  float* bf1 = (float*)take((size_t)(NE + 1) * HH * sizeof(float));
  float* bf3 = (float*)take((size_t)(NE + 1) * HH * sizeof(float));
  float* bf2 = (float*)take((size_t)(NE + 1) * DD * sizeof(float));
  int*   rows_tok = (int*)  take((size_t)TS * 2 * sizeof(int));
  float* rows_wgt = (float*)take((size_t)TS * 2 * sizeof(float));
  unsigned short* h_buf  = (unsigned short*)take((size_t)TS * 2 * HH * 2);
  unsigned short* sh_buf = (unsigned short*)take((size_t)TS * HH * 2);
  float* r_out = (float*)take((size_t)TS * 2 * DD * sizeof(float));

  sniff_kernel<<<1, 256, 0, stream>>>((const unsigned short*)x, dflag);

  cvtx_kernel<<<2048, 256, 0, stream>>>(x, dflag, xb, T * DD / 8);
  trans_kernel<<<dim3(HH / 32, DD / 32, NE + 1), 256, 0, stream>>>(w1, sw1, dflag, wt1, DD, HH);
  trans_kernel<<<dim3(HH / 32, DD / 32, NE + 1), 256, 0, stream>>>(w3, sw3, dflag, wt3, DD, HH);
  trans_kernel<<<dim3(DD / 32, HH / 32, NE + 1), 256, 0, stream>>>(w2, sw2, dflag, wt2, HH, DD);
  {
    int nb = (2 * (NE + 1) * HH + (NE + 1) * DD + 255) / 256;
    cvtb_kernel<<<nb, 256, 0, stream>>>(b1, b3, b2, sb1, sb3, sb2, dflag, bf1, bf3, bf2);
  }

  gate_kernel<<<(T + 3) / 4, 256, 0, stream>>>(x, gw, gb, dflag, tok_eidx, tok_w, T);

  // XCD-affinity 1-D grids
  const int upP = (HH / 128) * (NE + 1);    // 99
  const int dnP = (DD / 128) * (NE + 1);    // 72
  const int upGrid = 8 * ((upP + 7) / 8) * my;
  const int dnGrid = 8 * ((dnP + 7) / 8) * my;

  for (int s = 0; s < S; s++) {
    const int t0 = s * TS;
    prep_kernel<<<1, 1024, 0, stream>>>(tok_eidx, tok_w, meta, rows_tok, rows_wgt,
                                        tok_pos, t0, TS);
    ffn_up_kernel<<<upGrid, 512, 0, stream>>>(
        xb, wt1, wt3, bf1, bf3, meta, rows_tok, h_buf, sh_buf, t0, TS, my);
    ffn_down_kernel<<<dnGrid, 512, 0, stream>>>(
        h_buf, sh_buf, wt2, bf2, meta, rows_tok, rows_wgt, r_out,
        (float*)d_out, t0, TS, my);
    combine_kernel<<<1024, 256, 0, stream>>>((const float4*)r_out, tok_pos,
                                             (float4*)d_out, t0, TS);
  }
}